// Round 23
// baseline (613.037 us; speedup 1.0000x reference)
//
#include <hip/hip_runtime.h>
#include <hip/hip_fp16.h>
#include <math.h>

#define CCH 48
#define SDIM 32
#define SVOL (SDIM*SDIM*SDIM)
#define NB 2

typedef _Float16 half2_t __attribute__((ext_vector_type(2)));
typedef _Float16 half4_t __attribute__((ext_vector_type(4)));
typedef float float4_t __attribute__((ext_vector_type(4)));

static __device__ __forceinline__ float dot2f(half2_t a, half2_t b, float c) {
#if __has_builtin(__builtin_amdgcn_fdot2)
    return __builtin_amdgcn_fdot2(a, b, c, false);
#else
    return c + (float)a[0] * (float)b[0] + (float)a[1] * (float)b[1];
#endif
}

// ======== one-off weight reshape kernels ========

__global__ __launch_bounds__(256)
void reshape_pair_kernel(const float* __restrict__ w, half2_t* __restrict__ wt, int NO) {
    int i = blockIdx.x * 256 + threadIdx.x;
    int total = 27 * 24 * NO;
    if (i < total) {
        int o = i % NO; int rem = i / NO; int cp = rem % 24; int k = rem / 24;
        float w0 = w[((size_t)o * CCH + 2 * cp) * 27 + k];
        float w1 = w[((size_t)o * CCH + 2 * cp + 1) * 27 + k];
        wt[i] = half2_t{ (_Float16)w0, (_Float16)w1 };
    }
}

// off_w[81][48][27] -> MFMA A-fragments: entry e = (((tap*6+mt)*3+ks)*4+kq)*16+row
// holds half4 {W[mt*16+row][ks*16+kq*4+h], h=0..3}, zero-padded rows 81..95.
__global__ __launch_bounds__(256)
void reshape_mfma_off_kernel(const float* __restrict__ w, half4_t* __restrict__ wA) {
    int e = blockIdx.x * 256 + threadIdx.x;
    if (e < 31104) {
        int row = e & 15;
        int kq = (e >> 4) & 3;
        int ks = (e / 64) % 3;
        int mt = (e / 192) % 6;
        int tap = e / 1152;
        int o = mt * 16 + row;
        half4_t v;
        #pragma unroll
        for (int h = 0; h < 4; h++) {
            int ci = ks * 16 + kq * 4 + h;
            float val = (o < 81) ? w[((size_t)o * CCH + ci) * 27 + tap] : 0.f;
            v[h] = (_Float16)val;
        }
        wA[e] = v;
    }
}

__global__ __launch_bounds__(256)
void t1x1_pair_kernel(const float* __restrict__ w, half2_t* __restrict__ wt) {
    int i = blockIdx.x * 256 + threadIdx.x;
    if (i < 24 * CCH) {
        int o = i % CCH, cp = i / CCH;
        wt[i] = half2_t{ (_Float16)w[o * CCH + 2 * cp], (_Float16)w[o * CCH + 2 * cp + 1] };
    }
}

__global__ __launch_bounds__(256)
void t1x1_kernel(const float* __restrict__ w, float* __restrict__ wt) {
    int i = blockIdx.x * 256 + threadIdx.x;
    if (i < CCH * CCH) { int ci = i / CCH, o = i % CCH; wt[i] = w[o * CCH + ci]; }
}

__global__ __launch_bounds__(64)
void cb_kernel(const float* __restrict__ c1w, const float* __restrict__ c1b,
               const float* __restrict__ dcb, float* __restrict__ cb) {
    int o = threadIdx.x;
    if (o < CCH) {
        float v = c1b[o];
        for (int ci = 0; ci < CCH; ci++) v += c1w[o * CCH + ci] * dcb[ci];
        cb[o] = v;
    }
}

// ---------------- LayerNorm over C; writes fp32 xn AND half2-pair xnp ----------------
__global__ __launch_bounds__(256)
void ln_kernel(const float* __restrict__ x, const float* __restrict__ ln_s,
               const float* __restrict__ ln_b, float* __restrict__ xn,
               half2_t* __restrict__ xnp) {
    int s = blockIdx.x * 256 + threadIdx.x;
    int b = blockIdx.y;
    const float* xb = x + (size_t)b * CCH * SVOL + s;
    float v[CCH];
    float mu = 0.f;
    #pragma unroll
    for (int c = 0; c < CCH; c++) { v[c] = xb[c * SVOL]; mu += v[c]; }
    mu *= (1.0f / CCH);
    float var = 0.f;
    #pragma unroll
    for (int c = 0; c < CCH; c++) { float d = v[c] - mu; var += d * d; }
    var *= (1.0f / CCH);
    float inv = rsqrtf(var + 1e-5f);
    float* o = xn + (size_t)b * CCH * SVOL + s;
    float nv[CCH];
    #pragma unroll
    for (int c = 0; c < CCH; c++) { nv[c] = (v[c] - mu) * inv * ln_s[c] + ln_b[c]; o[c * SVOL] = nv[c]; }
    half2_t* xp = xnp + (size_t)b * 24 * SVOL + s;
    #pragma unroll
    for (int cp = 0; cp < 24; cp++)
        xp[(size_t)cp * SVOL] = half2_t{ (_Float16)nv[2 * cp], (_Float16)nv[2 * cp + 1] };
}

// ---------------- 1x1x1 conv + exact GELU (4 groups x 12), fp16 dot2 ----------------
__global__ __launch_bounds__(256, 4)
void p1_gelu_kernel(const half2_t* __restrict__ xnp, const half2_t* __restrict__ wt,
                    const float* __restrict__ bias, float* __restrict__ u) {
    int tid = threadIdx.x;
    int g = blockIdx.y, b = blockIdx.z;
    int s = blockIdx.x * 256 + tid;
    const half2_t* xb = xnp + (size_t)b * 24 * SVOL + s;
    float acc[12];
    #pragma unroll
    for (int o = 0; o < 12; o++) acc[o] = bias[g * 12 + o];
    for (int cp = 0; cp < 24; cp++) {
        half2_t v2 = xb[(size_t)cp * SVOL];
        const half2_t* wr = wt + cp * CCH + g * 12;
        #pragma unroll
        for (int o = 0; o < 12; o++) acc[o] = dot2f(v2, wr[o], acc[o]);
    }
    float* ub = u + (size_t)b * CCH * SVOL + s + (size_t)(g * 12) * SVOL;
    #pragma unroll
    for (int o = 0; o < 12; o++) {
        float a = acc[o];
        ub[o * SVOL] = 0.5f * a * (1.0f + erff(a * 0.70710678118654752f));
    }
}

// ---- depthwise 5x5x5 pad 2: half-column blocking (16 z/thread, window cache) ----
__global__ __launch_bounds__(256, 4)
void dw5_kernel(const float* __restrict__ in, const float* __restrict__ w,
                const float* __restrict__ bias, float* __restrict__ out) {
    int tid = threadIdx.x;
    int c = blockIdx.y, b = blockIdx.z;
    const float* wc = w + c * 125;
    int bx = blockIdx.x;
    int yx = (bx >> 1) * 256 + tid;
    int z0 = (bx & 1) * 16;
    int y = yx >> 5, xx = yx & 31;
    const float* ib = in + ((size_t)b * CCH + c) * SVOL;
    float acc[16];
    float bv = bias[c];
    #pragma unroll
    for (int z = 0; z < 16; z++) acc[z] = bv;
    for (int ty = 0; ty < 5; ty++) {
        int yy = y + ty - 2; if (yy < 0 || yy >= 32) continue;
        for (int tx = 0; tx < 5; tx++) {
            int xv = xx + tx - 2; if (xv < 0 || xv >= 32) continue;
            const float* col = ib + yy * 32 + xv;
            float cv[20];
            #pragma unroll
            for (int j = 0; j < 20; j++) {
                int zz = z0 - 2 + j;
                cv[j] = (zz >= 0 && zz < 32) ? col[(size_t)zz * 1024] : 0.f;
            }
            #pragma unroll
            for (int tz = 0; tz < 5; tz++) {
                float wv = wc[(tz * 5 + ty) * 5 + tx];
                #pragma unroll
                for (int z = 0; z < 16; z++) acc[z] += wv * cv[z + tz];
            }
        }
    }
    float* ob = out + ((size_t)b * CCH + c) * SVOL + y * 32 + xx;
    #pragma unroll
    for (int z = 0; z < 16; z++) ob[(size_t)(z0 + z) * 1024] = acc[z];
}

// ---- depthwise 7x7x7 dil 3 pad 9: half-column blocking (16 z/thread, window cache) ----
__global__ __launch_bounds__(256, 4)
void dw7_kernel(const float* __restrict__ in, const float* __restrict__ w,
                const float* __restrict__ bias, float* __restrict__ out) {
    int tid = threadIdx.x;
    int c = blockIdx.y, b = blockIdx.z;
    const float* wc = w + c * 343;
    int bx = blockIdx.x;
    int yx = (bx >> 1) * 256 + tid;
    int z0 = (bx & 1) * 16;
    int y = yx >> 5, xx = yx & 31;
    const float* ib = in + ((size_t)b * CCH + c) * SVOL;
    float acc[16];
    float bv = bias[c];
    #pragma unroll
    for (int z = 0; z < 16; z++) acc[z] = bv;
    for (int ty = 0; ty < 7; ty++) {
        int yy = y + 3 * (ty - 3); if (yy < 0 || yy >= 32) continue;
        for (int tx = 0; tx < 7; tx++) {
            int xv = xx + 3 * (tx - 3); if (xv < 0 || xv >= 32) continue;
            const float* col = ib + yy * 32 + xv;
            float cv[34];
            #pragma unroll
            for (int j = 0; j < 34; j++) {
                int zz = z0 - 9 + j;
                cv[j] = (zz >= 0 && zz < 32) ? col[(size_t)zz * 1024] : 0.f;
            }
            #pragma unroll
            for (int tz = 0; tz < 7; tz++) {
                float wv = wc[(tz * 7 + ty) * 7 + tx];
                #pragma unroll
                for (int z = 0; z < 16; z++) acc[z] += wv * cv[z + 3 * tz];
            }
        }
    }
    float* ob = out + ((size_t)b * CCH + c) * SVOL + y * 32 + xx;
    #pragma unroll
    for (int z = 0; z < 16; z++) ob[(size_t)(z0 + z) * 1024] = acc[z];
}

// ---- a1 fp32 [48][S] -> a1h fp16 [S][48] (deform + offconv operand) ----
__global__ __launch_bounds__(256)
void transpose_pack_kernel(const float* __restrict__ a1, __half* __restrict__ a1h) {
    __shared__ float tile[CCH * 65];
    int tid = threadIdx.x;
    int b = blockIdx.y;
    int s0 = blockIdx.x * 64;
    const float* ib = a1 + (size_t)b * CCH * SVOL + s0;
    for (int i = tid; i < CCH * 64; i += 256) {
        int c = i >> 6, p = i & 63;
        tile[c * 65 + p] = ib[(size_t)c * SVOL + p];
    }
    __syncthreads();
    __half* ob = a1h + ((size_t)b * SVOL + s0) * CCH;
    for (int i = tid; i < 64 * CCH; i += 256) {
        int p = i / CCH, c = i % CCH;
        ob[i] = __float2half(tile[c * 65 + p]);
    }
}

// ---- offset conv 3x3x3 via MFMA implicit-GEMM: 4x4x4 tile, halo in LDS, no atomics ----
__global__ __launch_bounds__(256, 4)
void offconv_mfma_kernel(const __half* __restrict__ a1h, const half4_t* __restrict__ wA,
                         float* __restrict__ off) {
    __shared__ __half halo[216 * 52];     // [6x6x6 pos][48 ch + 4 pad], 22.5 KB
    int tid = threadIdx.x;
    int t = blockIdx.x;                    // 0..511 spatial tile
    int b = blockIdx.y;
    int tz0 = (t >> 6) * 4, ty0 = ((t >> 3) & 7) * 4, tx0 = (t & 7) * 4;
    const __half* ab = a1h + (size_t)b * SVOL * CCH;
    for (int idx = tid; idx < 216 * 24; idx += 256) {
        int hpos = idx / 24, kp = idx % 24;
        int hz = hpos / 36, hy = (hpos / 6) % 6, hx = hpos % 6;
        int gz = tz0 + hz - 1, gy = ty0 + hy - 1, gx = tx0 + hx - 1;
        unsigned int v = 0u;
        if (gz >= 0 && gz < 32 && gy >= 0 && gy < 32 && gx >= 0 && gx < 32) {
            int s = (gz * 32 + gy) * 32 + gx;
            v = *reinterpret_cast<const unsigned int*>(ab + (size_t)s * CCH + kp * 2);
        }
        *reinterpret_cast<unsigned int*>(&halo[hpos * 52 + kp * 2]) = v;
    }
    __syncthreads();
    int wave = tid >> 6, lane = tid & 63;
    int col = lane & 15;                   // position col / A row
    int kq = lane >> 4;                    // k-quad 0..3
    int py = col >> 2, px = col & 3;
    int pz = wave;
    float4_t acc[6];
    #pragma unroll
    for (int m = 0; m < 6; m++) acc[m] = (float4_t)0.f;
    for (int tap = 0; tap < 27; tap++) {
        int dz = tap / 9, dy = (tap / 3) % 3, dx = tap % 3;
        int hbase = ((pz + dz) * 36 + (py + dy) * 6 + (px + dx)) * 52 + kq * 4;
        half4_t bf0 = *reinterpret_cast<const half4_t*>(&halo[hbase]);
        half4_t bf1 = *reinterpret_cast<const half4_t*>(&halo[hbase + 16]);
        half4_t bf2 = *reinterpret_cast<const half4_t*>(&halo[hbase + 32]);
        #pragma unroll
        for (int mt = 0; mt < 6; mt++) {
            int fb = (tap * 6 + mt) * 12 + kq;     // f index for ks=0
            half4_t a0 = wA[(size_t)fb * 16 + col];
            half4_t a1 = wA[(size_t)(fb + 4) * 16 + col];
            half4_t a2 = wA[(size_t)(fb + 8) * 16 + col];
            acc[mt] = __builtin_amdgcn_mfma_f32_16x16x16f16(a0, bf0, acc[mt], 0, 0, 0);
            acc[mt] = __builtin_amdgcn_mfma_f32_16x16x16f16(a1, bf1, acc[mt], 0, 0, 0);
            acc[mt] = __builtin_amdgcn_mfma_f32_16x16x16f16(a2, bf2, acc[mt], 0, 0, 0);
        }
    }
    int sg = ((tz0 + pz) * 32 + ty0 + py) * 32 + tx0 + px;
    float* ob = off + (size_t)b * 81 * SVOL + sg;
    #pragma unroll
    for (int mt = 0; mt < 6; mt++) {
        #pragma unroll
        for (int r = 0; r < 4; r++) {
            int orow = mt * 16 + kq * 4 + r;
            if (orow < 81) ob[(size_t)orow * SVOL] = acc[mt][r];
        }
    }
}

// ---- deformable conv 3x3x3: ci-split 3 (16 ch), packed fp16 interp + dot2 matmul ----
struct h8v { half2_t a, b, c, d; };   // 16 bytes = 8 halves

__global__ __launch_bounds__(256, 4)
void deform_kernel(const __half* __restrict__ a1h, const float* __restrict__ off,
                   const float* __restrict__ off_b,
                   const half2_t* __restrict__ wt, float* __restrict__ out) {
    int tid = threadIdx.x;
    int gc = blockIdx.y;            // ci group 0..2 (16 ch = 8 pairs each)
    int b = blockIdx.z;
    int s = blockIdx.x * 256 + tid;
    int z = s >> 10, y = (s >> 5) & 31, xx = s & 31;
    const __half* abase = a1h + (size_t)b * SVOL * CCH + gc * 16;
    const float* ob = off + (size_t)b * 81 * SVOL + s;
    float acc[CCH];
    #pragma unroll
    for (int o = 0; o < CCH; o++) acc[o] = 0.f;
    for (int k = 0; k < 27; k++) {
        int kd = k / 9 - 1, kh = (k / 3) % 3 - 1, kw = k % 3 - 1;
        float zf = (float)(z + kd) + ob[(size_t)(k * 3 + 0) * SVOL] + off_b[k * 3 + 0];
        float yf = (float)(y + kh) + ob[(size_t)(k * 3 + 1) * SVOL] + off_b[k * 3 + 1];
        float xf = (float)(xx + kw) + ob[(size_t)(k * 3 + 2) * SVOL] + off_b[k * 3 + 2];
        float z0 = floorf(zf), y0 = floorf(yf), x0 = floorf(xf);
        float tz = zf - z0, ty = yf - y0, tx = xf - x0;
        int iz0 = (int)z0, iy0 = (int)y0, ix0 = (int)x0;
        half2_t val2[8];
        #pragma unroll
        for (int j = 0; j < 8; j++) val2[j] = (half2_t)(_Float16)0;
        #pragma unroll
        for (int corner = 0; corner < 8; corner++) {
            int dz = corner >> 2, dy = (corner >> 1) & 1, dx = corner & 1;
            int zi = iz0 + dz, yi = iy0 + dy, xi = ix0 + dx;
            bool valid = (zi >= 0 && zi < 32 && yi >= 0 && yi < 32 && xi >= 0 && xi < 32);
            float wgt = (dz ? tz : 1.f - tz) * (dy ? ty : 1.f - ty) * (dx ? tx : 1.f - tx);
            float cwv = valid ? wgt : 0.f;
            _Float16 cwh = (_Float16)cwv;
            half2_t cw2 = { cwh, cwh };
            int zc = min(max(zi, 0), 31), yc = min(max(yi, 0), 31), xc = min(max(xi, 0), 31);
            int cidx = (zc * 32 + yc) * 32 + xc;
            const h8v* pv = (const h8v*)(abase + (size_t)cidx * CCH);
            h8v q0 = pv[0], q1 = pv[1];
            val2[0] += cw2 * q0.a;  val2[1] += cw2 * q0.b;
            val2[2] += cw2 * q0.c;  val2[3] += cw2 * q0.d;
            val2[4] += cw2 * q1.a;  val2[5] += cw2 * q1.b;
            val2[6] += cw2 * q1.c;  val2[7] += cw2 * q1.d;
        }
        #pragma unroll
        for (int cpl = 0; cpl < 8; cpl++) {
            half2_t v2 = val2[cpl];
            const half2_t* wr = wt + ((size_t)k * 24 + gc * 8 + cpl) * CCH;  // uniform
            #pragma unroll
            for (int o = 0; o < CCH; o++) acc[o] = dot2f(v2, wr[o], acc[o]);
        }
    }
    float* op = out + (size_t)b * CCH * SVOL + s;
    #pragma unroll
    for (int o = 0; o < CCH; o++) atomicAdd(&op[(size_t)o * SVOL], acc[o]);
}

// ---- gate1: a2 = (c1 . dc + cb) * u; writes half2-pair a2p ----
__global__ __launch_bounds__(256, 4)
void gate1_kernel(const float* __restrict__ dc, const float* __restrict__ u,
                  const float* __restrict__ wt, const float* __restrict__ cb,
                  half2_t* __restrict__ a2p) {
    int tid = threadIdx.x;
    int g = blockIdx.y, b = blockIdx.z;
    int s = blockIdx.x * 256 + tid;
    size_t base = (size_t)b * CCH * SVOL + s;
    float acc[12];
    #pragma unroll
    for (int o = 0; o < 12; o++) acc[o] = cb[g * 12 + o];
    for (int ci = 0; ci < CCH; ci++) {
        float v = dc[base + (size_t)ci * SVOL];
        const float* wr = wt + ci * CCH + g * 12;
        #pragma unroll
        for (int o = 0; o < 12; o++) acc[o] += wr[o] * v;
    }
    #pragma unroll
    for (int o = 0; o < 12; o++) acc[o] *= u[base + (size_t)(g * 12 + o) * SVOL];
    half2_t* ap = a2p + ((size_t)b * 24 + g * 6) * SVOL + s;
    #pragma unroll
    for (int j = 0; j < 6; j++)
        ap[(size_t)j * SVOL] = half2_t{ (_Float16)acc[2 * j], (_Float16)acc[2 * j + 1] };
}

// ---- gate2: skip = x + gamma*(p2 . a2 + p2b + xn), fp16 dot2; writes fp32 skip + half2 skp ----
__global__ __launch_bounds__(256, 4)
void gate2_kernel(const half2_t* __restrict__ a2p, const float* __restrict__ xn,
                  const float* __restrict__ x,
                  const half2_t* __restrict__ wt, const float* __restrict__ p2b,
                  const float* __restrict__ gamma, float* __restrict__ skip,
                  half2_t* __restrict__ skp) {
    int tid = threadIdx.x;
    int g = blockIdx.y, b = blockIdx.z;
    int s = blockIdx.x * 256 + tid;
    size_t base = (size_t)b * CCH * SVOL + s;
    const half2_t* ab = a2p + (size_t)b * 24 * SVOL + s;
    float acc[12];
    #pragma unroll
    for (int o = 0; o < 12; o++) acc[o] = p2b[g * 12 + o];
    for (int cp = 0; cp < 24; cp++) {
        half2_t v2 = ab[(size_t)cp * SVOL];
        const half2_t* wr = wt + cp * CCH + g * 12;
        #pragma unroll
        for (int o = 0; o < 12; o++) acc[o] = dot2f(v2, wr[o], acc[o]);
    }
    float sv[12];
    #pragma unroll
    for (int o = 0; o < 12; o++) {
        int oc = g * 12 + o;
        float vv = acc[o] + xn[base + (size_t)oc * SVOL];
        sv[o] = x[base + (size_t)oc * SVOL] + gamma[oc] * vv;
        skip[base + (size_t)oc * SVOL] = sv[o];
    }
    half2_t* sp = skp + ((size_t)b * 24 + g * 6) * SVOL + s;
    #pragma unroll
    for (int j = 0; j < 6; j++)
        sp[(size_t)j * SVOL] = half2_t{ (_Float16)sv[2 * j], (_Float16)sv[2 * j + 1] };
}

// ---- u1: 3x3x3 conv + BN1 + LeakyReLU, fp16 dot2; writes packed half2 output ----
__global__ __launch_bounds__(256, 4)
void u1_kernel(const half2_t* __restrict__ skp, const half2_t* __restrict__ wt,
               const float* __restrict__ bs, const float* __restrict__ bb,
               const float* __restrict__ bm, const float* __restrict__ bv,
               half2_t* __restrict__ h1p) {
    int tid = threadIdx.x;
    int g = blockIdx.y, b = blockIdx.z;
    int s = blockIdx.x * 256 + tid;
    int z = s >> 10, y = (s >> 5) & 31, xx = s & 31;
    const half2_t* ib = skp + (size_t)b * 24 * SVOL;
    float acc[12];
    #pragma unroll
    for (int o = 0; o < 12; o++) acc[o] = 0.f;
    for (int tap = 0; tap < 27; tap++) {
        int dz = tap / 9 - 1, dy = (tap / 3) % 3 - 1, dx = tap % 3 - 1;
        int zz = z + dz, yy = y + dy, xv = xx + dx;
        bool ok = (zz >= 0 && zz < 32 && yy >= 0 && yy < 32 && xv >= 0 && xv < 32);
        if (ok) {
            int si = (zz * 32 + yy) * 32 + xv;
            for (int cp = 0; cp < 24; cp++) {
                half2_t v2 = ib[(size_t)cp * SVOL + si];
                const half2_t* wr = wt + ((size_t)tap * 24 + cp) * CCH + g * 12;  // uniform
                #pragma unroll
                for (int o = 0; o < 12; o++) acc[o] = dot2f(v2, wr[o], acc[o]);
            }
        }
    }
    float hv[12];
    #pragma unroll
    for (int o = 0; o < 12; o++) {
        int oc = g * 12 + o;
        float inv = rsqrtf(bv[oc] + 1e-5f);
        float h = (acc[o] - bm[oc]) * (bs[oc] * inv) + bb[oc];
        hv[o] = h >= 0.f ? h : 0.01f * h;
    }
    half2_t* op = h1p + ((size_t)b * 24 + g * 6) * SVOL + s;
    #pragma unroll
    for (int j = 0; j < 6; j++)
        op[(size_t)j * SVOL] = half2_t{ (_Float16)hv[2 * j], (_Float16)hv[2 * j + 1] };
}

// ---- u2_bn: 3x3x3 conv (fp16 dot2) + BN2 + (+skip fp32) + LeakyReLU -> attnp half2 ----
__global__ __launch_bounds__(256, 4)
void u2_bn_kernel(const half2_t* __restrict__ h1p, const float* __restrict__ skip,
                  const half2_t* __restrict__ wt,
                  const float* __restrict__ bs, const float* __restrict__ bb,
                  const float* __restrict__ bm, const float* __restrict__ bv,
                  half2_t* __restrict__ attnp) {
    int tid = threadIdx.x;
    int g = blockIdx.y, b = blockIdx.z;
    int s = blockIdx.x * 256 + tid;
    int z = s >> 10, y = (s >> 5) & 31, xx = s & 31;
    const half2_t* ib = h1p + (size_t)b * 24 * SVOL;
    float acc[12];
    #pragma unroll
    for (int o = 0; o < 12; o++) acc[o] = 0.f;
    for (int tap = 0; tap < 27; tap++) {
        int dz = tap / 9 - 1, dy = (tap / 3) % 3 - 1, dx = tap % 3 - 1;
        int zz = z + dz, yy = y + dy, xv = xx + dx;
        bool ok = (zz >= 0 && zz < 32 && yy >= 0 && yy < 32 && xv >= 0 && xv < 32);
        if (ok) {
            int si = (zz * 32 + yy) * 32 + xv;
            for (int cp = 0; cp < 24; cp++) {
                half2_t v2 = ib[(size_t)cp * SVOL + si];
                const half2_t* wr = wt + ((size_t)tap * 24 + cp) * CCH + g * 12;  // uniform
                #pragma unroll
                for (int o = 0; o < 12; o++) acc[o] = dot2f(v2, wr[o], acc[o]);
            }
        }
    }
    size_t base = (size_t)b * CCH * SVOL + s;
    float av[12];
    #pragma unroll
    for (int o = 0; o < 12; o++) {
        int oc = g * 12 + o;
        float inv = rsqrtf(bv[oc] + 1e-5f);
        float h = (acc[o] - bm[oc]) * (bs[oc] * inv) + bb[oc];
        float a = h + skip[base + (size_t)oc * SVOL];
        av[o] = a >= 0.f ? a : 0.01f * a;
    }
    half2_t* op = attnp + ((size_t)b * 24 + g * 6) * SVOL + s;
    #pragma unroll
    for (int j = 0; j < 6; j++)
        op[(size_t)j * SVOL] = half2_t{ (_Float16)av[2 * j], (_Float16)av[2 * j + 1] };
}

// ---- pr_final: out = skip + pr(attn), fp16 dot2 ----
__global__ __launch_bounds__(256, 4)
void pr_final_kernel(const half2_t* __restrict__ attnp, const float* __restrict__ skip,
                     const half2_t* __restrict__ wt, const float* __restrict__ prb,
                     float* __restrict__ out) {
    int tid = threadIdx.x;
    int g = blockIdx.y, b = blockIdx.z;
    int s = blockIdx.x * 256 + tid;
    size_t base = (size_t)b * CCH * SVOL + s;
    const half2_t* ab = attnp + (size_t)b * 24 * SVOL + s;
    float acc[12];
    #pragma unroll
    for (int o = 0; o < 12; o++) acc[o] = prb[g * 12 + o];
    for (int cp = 0; cp < 24; cp++) {
        half2_t v2 = ab[(size_t)cp * SVOL];
        const half2_t* wr = wt + cp * CCH + g * 12;
        #pragma unroll
        for (int o = 0; o < 12; o++) acc[o] = dot2f(v2, wr[o], acc[o]);
    }
    #pragma unroll
    for (int o = 0; o < 12; o++) {
        int oc = g * 12 + o;
        out[base + (size_t)oc * SVOL] = skip[base + (size_t)oc * SVOL] + acc[o];
    }
}

extern "C" void kernel_launch(void* const* d_in, const int* in_sizes, int n_in,
                              void* d_out, int out_size, void* d_ws, size_t ws_size,
                              hipStream_t stream) {
    (void)in_sizes; (void)n_in; (void)out_size; (void)ws_size;
    const float* x     = (const float*)d_in[0];
    const float* ln_s  = (const float*)d_in[1];
    const float* ln_b  = (const float*)d_in[2];
    const float* gamma = (const float*)d_in[3];
    const float* p1_w  = (const float*)d_in[4];
    const float* p1_b  = (const float*)d_in[5];
    const float* p2_w  = (const float*)d_in[6];
    const float* p2_b  = (const float*)d_in[7];
    const float* c0_w  = (const float*)d_in[8];
    const float* c0_b  = (const float*)d_in[9];
    const float* cs_w  = (const float*)d_in[10];
    const float* cs_b  = (const float*)d_in[11];
    const float* off_w = (const float*)d_in[12];
    const float* off_b = (const float*)d_in[13];
    const float* dc_w  = (const float*)d_in[14];
    const float* dc_b  = (const float*)d_in[15];
    const float* c1_w  = (const float*)d_in[16];
    const float* c1_b  = (const float*)d_in[17];
    const float* u1_w  = (const float*)d_in[18];
    const float* bn1_s = (const float*)d_in[19];
    const float* bn1_b = (const float*)d_in[20];
    const float* bn1_m = (const float*)d_in[21];
    const float* bn1_v = (const float*)d_in[22];
    const float* u2_w  = (const float*)d_in[23];
    const float* bn2_s = (const float*)d_in[24];
    const float* bn2_b = (const float*)d_in[25];
    const float* bn2_m = (const float*)d_in[26];
    const float* bn2_v = (const float*)d_in[27];
    const float* pr_w  = (const float*)d_in[28];
    const float* pr_b  = (const float*)d_in[29];
    float* out = (float*)d_out;

    float* wsf = (float*)d_ws;
    const size_t TS = (size_t)NB * CCH * SVOL;   // 3,145,728 floats
    float* xn   = out;            // d_out doubles as xn fp32 (dead after gate2)
    float* ubuf = wsf;            // u (gelu out fp32) -> [skp | h1p] (half2)
    float* bufA = wsf + TS;       // dw5 out -> a1h -> skip (fp32)
    float* bufB = wsf + 2 * TS;   // xnp (half2) -> dw7 out (a1) -> deform partials (dc)
    float* offb = wsf + 3 * TS;   // offsets [B,81,S] -> a2p (half2) -> attnp (half2)
    float* wtb    = wsf + 3 * TS + (size_t)NB * 81 * SVOL;
    float* wt_offf = wtb;                   // MFMA A frags: 31104 half4 = 62208 floats
    float* wt_dcf  = wt_offf + 104976;
    float* wt_u1f  = wt_dcf + 62208;
    float* wt_u2f  = wt_u1f + 62208;
    float* pt_p1  = wt_u2f + 62208;
    float* pt_c1  = pt_p1 + 2304;
    float* pt_p2  = pt_c1 + 2304;
    float* pt_pr  = pt_p2 + 2304;
    float* cb_all = pt_pr + 2304;

    __half*  a1h = (__half*)bufA;
    half2_t* skp = (half2_t*)ubuf;
    half2_t* h1p = (half2_t*)(ubuf + TS / 2);
    half2_t* xnp = (half2_t*)bufB;
    half2_t* a2p = (half2_t*)offb;
    half2_t* attnp = (half2_t*)offb;
    half4_t* wA_off = (half4_t*)wt_offf;
    half2_t* wt_dch  = (half2_t*)wt_dcf;
    half2_t* wt_u1h  = (half2_t*)wt_u1f;
    half2_t* wt_u2h  = (half2_t*)wt_u2f;
    half2_t* wt_p1h  = (half2_t*)pt_p1;
    half2_t* wt_p2h  = (half2_t*)pt_p2;
    half2_t* wt_prh  = (half2_t*)pt_pr;

    dim3 blk(256);
    dim3 gpos(SVOL / 256, NB);
    dim3 g4(SVOL / 256, 4, NB);
    dim3 gmf(512, NB);                 // offconv MFMA: 8x8x8 spatial tiles
    dim3 g3d(SVOL / 256, 3, NB);
    dim3 gdwc(8, CCH, NB);
    dim3 gtr(SVOL / 64, NB);

    hipLaunchKernelGGL(reshape_mfma_off_kernel, dim3((31104 + 255) / 256), blk, 0, stream, off_w, wA_off);
    hipLaunchKernelGGL(reshape_pair_kernel, dim3((27 * 24 * 48 + 255) / 256), blk, 0, stream, dc_w,  wt_dch,  48);
    hipLaunchKernelGGL(reshape_pair_kernel, dim3((27 * 24 * 48 + 255) / 256), blk, 0, stream, u1_w,  wt_u1h,  48);
    hipLaunchKernelGGL(reshape_pair_kernel, dim3((27 * 24 * 48 + 255) / 256), blk, 0, stream, u2_w,  wt_u2h,  48);
    hipLaunchKernelGGL(t1x1_pair_kernel, dim3(5), blk, 0, stream, p1_w, wt_p1h);
    hipLaunchKernelGGL(t1x1_pair_kernel, dim3(5), blk, 0, stream, p2_w, wt_p2h);
    hipLaunchKernelGGL(t1x1_pair_kernel, dim3(5), blk, 0, stream, pr_w, wt_prh);
    hipLaunchKernelGGL(t1x1_kernel, dim3(9), blk, 0, stream, c1_w, pt_c1);
    hipLaunchKernelGGL(cb_kernel, dim3(1), dim3(64), 0, stream, c1_w, c1_b, dc_b, cb_all);

    hipLaunchKernelGGL(ln_kernel,            gpos, blk, 0, stream, x, ln_s, ln_b, xn, xnp);
    hipLaunchKernelGGL(p1_gelu_kernel,       g4,   blk, 0, stream, xnp, wt_p1h, p1_b, ubuf);
    hipLaunchKernelGGL(dw5_kernel,           gdwc, blk, 0, stream, ubuf, c0_w, c0_b, bufA);
    hipLaunchKernelGGL(dw7_kernel,           gdwc, blk, 0, stream, bufA, cs_w, cs_b, bufB);
    hipLaunchKernelGGL(transpose_pack_kernel, gtr, blk, 0, stream, bufB, a1h);
    hipLaunchKernelGGL(offconv_mfma_kernel,  gmf,  blk, 0, stream, a1h, wA_off, offb);
    hipMemsetAsync(bufB, 0, TS * sizeof(float), stream);
    hipLaunchKernelGGL(deform_kernel,        g3d,  blk, 0, stream, a1h, offb, off_b, wt_dch, bufB);
    hipLaunchKernelGGL(gate1_kernel,         g4,   blk, 0, stream, bufB, ubuf, pt_c1, cb_all, a2p);
    hipLaunchKernelGGL(gate2_kernel,         g4,   blk, 0, stream, a2p, xn, x, wt_p2h, p2_b, gamma,
                       bufA, skp);
    hipLaunchKernelGGL(u1_kernel,            g4,   blk, 0, stream, skp, wt_u1h,
                       bn1_s, bn1_b, bn1_m, bn1_v, h1p);
    hipLaunchKernelGGL(u2_bn_kernel,         g4,   blk, 0, stream, h1p, bufA, wt_u2h,
                       bn2_s, bn2_b, bn2_m, bn2_v, attnp);
    hipLaunchKernelGGL(pr_final_kernel,      g4,   blk, 0, stream, attnp, bufA, wt_prh, pr_b, out);
}

// Round 24
// 610.821 us; speedup vs baseline: 1.0036x; 1.0036x over previous
//
#include <hip/hip_runtime.h>
#include <hip/hip_fp16.h>
#include <math.h>

#define CCH 48
#define SDIM 32
#define SVOL (SDIM*SDIM*SDIM)
#define NB 2

typedef _Float16 half2_t __attribute__((ext_vector_type(2)));
typedef _Float16 half4_t __attribute__((ext_vector_type(4)));
typedef float float4_t __attribute__((ext_vector_type(4)));

static __device__ __forceinline__ float dot2f(half2_t a, half2_t b, float c) {
#if __has_builtin(__builtin_amdgcn_fdot2)
    return __builtin_amdgcn_fdot2(a, b, c, false);
#else
    return c + (float)a[0] * (float)b[0] + (float)a[1] * (float)b[1];
#endif
}

// ======== one-off weight reshape kernels ========

__global__ __launch_bounds__(256)
void reshape_pair_kernel(const float* __restrict__ w, half2_t* __restrict__ wt, int NO) {
    int i = blockIdx.x * 256 + threadIdx.x;
    int total = 27 * 24 * NO;
    if (i < total) {
        int o = i % NO; int rem = i / NO; int cp = rem % 24; int k = rem / 24;
        float w0 = w[((size_t)o * CCH + 2 * cp) * 27 + k];
        float w1 = w[((size_t)o * CCH + 2 * cp + 1) * 27 + k];
        wt[i] = half2_t{ (_Float16)w0, (_Float16)w1 };
    }
}

// off_w[81][48][27] -> MFMA A-fragments: entry e = (((tap*6+mt)*3+ks)*4+kq)*16+row
// holds half4 {W[mt*16+row][ks*16+kq*4+h], h=0..3}, zero-padded rows 81..95.
__global__ __launch_bounds__(256)
void reshape_mfma_off_kernel(const float* __restrict__ w, half4_t* __restrict__ wA) {
    int e = blockIdx.x * 256 + threadIdx.x;
    if (e < 31104) {
        int row = e & 15;
        int kq = (e >> 4) & 3;
        int ks = (e / 64) % 3;
        int mt = (e / 192) % 6;
        int tap = e / 1152;
        int o = mt * 16 + row;
        half4_t v;
        #pragma unroll
        for (int h = 0; h < 4; h++) {
            int ci = ks * 16 + kq * 4 + h;
            float val = (o < 81) ? w[((size_t)o * CCH + ci) * 27 + tap] : 0.f;
            v[h] = (_Float16)val;
        }
        wA[e] = v;
    }
}

__global__ __launch_bounds__(256)
void t1x1_pair_kernel(const float* __restrict__ w, half2_t* __restrict__ wt) {
    int i = blockIdx.x * 256 + threadIdx.x;
    if (i < 24 * CCH) {
        int o = i % CCH, cp = i / CCH;
        wt[i] = half2_t{ (_Float16)w[o * CCH + 2 * cp], (_Float16)w[o * CCH + 2 * cp + 1] };
    }
}

__global__ __launch_bounds__(256)
void t1x1_kernel(const float* __restrict__ w, float* __restrict__ wt) {
    int i = blockIdx.x * 256 + threadIdx.x;
    if (i < CCH * CCH) { int ci = i / CCH, o = i % CCH; wt[i] = w[o * CCH + ci]; }
}

__global__ __launch_bounds__(64)
void cb_kernel(const float* __restrict__ c1w, const float* __restrict__ c1b,
               const float* __restrict__ dcb, float* __restrict__ cb) {
    int o = threadIdx.x;
    if (o < CCH) {
        float v = c1b[o];
        for (int ci = 0; ci < CCH; ci++) v += c1w[o * CCH + ci] * dcb[ci];
        cb[o] = v;
    }
}

// ---------------- LayerNorm over C; writes fp32 xn AND half2-pair xnp ----------------
__global__ __launch_bounds__(256)
void ln_kernel(const float* __restrict__ x, const float* __restrict__ ln_s,
               const float* __restrict__ ln_b, float* __restrict__ xn,
               half2_t* __restrict__ xnp) {
    int s = blockIdx.x * 256 + threadIdx.x;
    int b = blockIdx.y;
    const float* xb = x + (size_t)b * CCH * SVOL + s;
    float v[CCH];
    float mu = 0.f;
    #pragma unroll
    for (int c = 0; c < CCH; c++) { v[c] = xb[c * SVOL]; mu += v[c]; }
    mu *= (1.0f / CCH);
    float var = 0.f;
    #pragma unroll
    for (int c = 0; c < CCH; c++) { float d = v[c] - mu; var += d * d; }
    var *= (1.0f / CCH);
    float inv = rsqrtf(var + 1e-5f);
    float* o = xn + (size_t)b * CCH * SVOL + s;
    float nv[CCH];
    #pragma unroll
    for (int c = 0; c < CCH; c++) { nv[c] = (v[c] - mu) * inv * ln_s[c] + ln_b[c]; o[c * SVOL] = nv[c]; }
    half2_t* xp = xnp + (size_t)b * 24 * SVOL + s;
    #pragma unroll
    for (int cp = 0; cp < 24; cp++)
        xp[(size_t)cp * SVOL] = half2_t{ (_Float16)nv[2 * cp], (_Float16)nv[2 * cp + 1] };
}

// ---------------- 1x1x1 conv + exact GELU (4 groups x 12), fp16 dot2 ----------------
__global__ __launch_bounds__(256, 4)
void p1_gelu_kernel(const half2_t* __restrict__ xnp, const half2_t* __restrict__ wt,
                    const float* __restrict__ bias, float* __restrict__ u) {
    int tid = threadIdx.x;
    int g = blockIdx.y, b = blockIdx.z;
    int s = blockIdx.x * 256 + tid;
    const half2_t* xb = xnp + (size_t)b * 24 * SVOL + s;
    float acc[12];
    #pragma unroll
    for (int o = 0; o < 12; o++) acc[o] = bias[g * 12 + o];
    for (int cp = 0; cp < 24; cp++) {
        half2_t v2 = xb[(size_t)cp * SVOL];
        const half2_t* wr = wt + cp * CCH + g * 12;
        #pragma unroll
        for (int o = 0; o < 12; o++) acc[o] = dot2f(v2, wr[o], acc[o]);
    }
    float* ub = u + (size_t)b * CCH * SVOL + s + (size_t)(g * 12) * SVOL;
    #pragma unroll
    for (int o = 0; o < 12; o++) {
        float a = acc[o];
        ub[o * SVOL] = 0.5f * a * (1.0f + erff(a * 0.70710678118654752f));
    }
}

// ---- depthwise 5x5x5 pad 2: half-column blocking (16 z/thread, window cache) ----
__global__ __launch_bounds__(256, 4)
void dw5_kernel(const float* __restrict__ in, const float* __restrict__ w,
                const float* __restrict__ bias, float* __restrict__ out) {
    int tid = threadIdx.x;
    int c = blockIdx.y, b = blockIdx.z;
    const float* wc = w + c * 125;
    int bx = blockIdx.x;
    int yx = (bx >> 1) * 256 + tid;
    int z0 = (bx & 1) * 16;
    int y = yx >> 5, xx = yx & 31;
    const float* ib = in + ((size_t)b * CCH + c) * SVOL;
    float acc[16];
    float bv = bias[c];
    #pragma unroll
    for (int z = 0; z < 16; z++) acc[z] = bv;
    for (int ty = 0; ty < 5; ty++) {
        int yy = y + ty - 2; if (yy < 0 || yy >= 32) continue;
        for (int tx = 0; tx < 5; tx++) {
            int xv = xx + tx - 2; if (xv < 0 || xv >= 32) continue;
            const float* col = ib + yy * 32 + xv;
            float cv[20];
            #pragma unroll
            for (int j = 0; j < 20; j++) {
                int zz = z0 - 2 + j;
                cv[j] = (zz >= 0 && zz < 32) ? col[(size_t)zz * 1024] : 0.f;
            }
            #pragma unroll
            for (int tz = 0; tz < 5; tz++) {
                float wv = wc[(tz * 5 + ty) * 5 + tx];
                #pragma unroll
                for (int z = 0; z < 16; z++) acc[z] += wv * cv[z + tz];
            }
        }
    }
    float* ob = out + ((size_t)b * CCH + c) * SVOL + y * 32 + xx;
    #pragma unroll
    for (int z = 0; z < 16; z++) ob[(size_t)(z0 + z) * 1024] = acc[z];
}

// ---- depthwise 7x7x7 dil 3 pad 9: half-column blocking (16 z/thread, window cache) ----
__global__ __launch_bounds__(256, 4)
void dw7_kernel(const float* __restrict__ in, const float* __restrict__ w,
                const float* __restrict__ bias, float* __restrict__ out) {
    int tid = threadIdx.x;
    int c = blockIdx.y, b = blockIdx.z;
    const float* wc = w + c * 343;
    int bx = blockIdx.x;
    int yx = (bx >> 1) * 256 + tid;
    int z0 = (bx & 1) * 16;
    int y = yx >> 5, xx = yx & 31;
    const float* ib = in + ((size_t)b * CCH + c) * SVOL;
    float acc[16];
    float bv = bias[c];
    #pragma unroll
    for (int z = 0; z < 16; z++) acc[z] = bv;
    for (int ty = 0; ty < 7; ty++) {
        int yy = y + 3 * (ty - 3); if (yy < 0 || yy >= 32) continue;
        for (int tx = 0; tx < 7; tx++) {
            int xv = xx + 3 * (tx - 3); if (xv < 0 || xv >= 32) continue;
            const float* col = ib + yy * 32 + xv;
            float cv[34];
            #pragma unroll
            for (int j = 0; j < 34; j++) {
                int zz = z0 - 9 + j;
                cv[j] = (zz >= 0 && zz < 32) ? col[(size_t)zz * 1024] : 0.f;
            }
            #pragma unroll
            for (int tz = 0; tz < 7; tz++) {
                float wv = wc[(tz * 7 + ty) * 7 + tx];
                #pragma unroll
                for (int z = 0; z < 16; z++) acc[z] += wv * cv[z + 3 * tz];
            }
        }
    }
    float* ob = out + ((size_t)b * CCH + c) * SVOL + y * 32 + xx;
    #pragma unroll
    for (int z = 0; z < 16; z++) ob[(size_t)(z0 + z) * 1024] = acc[z];
}

// ---- a1 fp32 [48][S] -> a1h fp16 [S][48] (deform + offconv operand) ----
__global__ __launch_bounds__(256)
void transpose_pack_kernel(const float* __restrict__ a1, __half* __restrict__ a1h) {
    __shared__ float tile[CCH * 65];
    int tid = threadIdx.x;
    int b = blockIdx.y;
    int s0 = blockIdx.x * 64;
    const float* ib = a1 + (size_t)b * CCH * SVOL + s0;
    for (int i = tid; i < CCH * 64; i += 256) {
        int c = i >> 6, p = i & 63;
        tile[c * 65 + p] = ib[(size_t)c * SVOL + p];
    }
    __syncthreads();
    __half* ob = a1h + ((size_t)b * SVOL + s0) * CCH;
    for (int i = tid; i < 64 * CCH; i += 256) {
        int p = i / CCH, c = i % CCH;
        ob[i] = __float2half(tile[c * 65 + p]);
    }
}

// ---- offset conv 3x3x3 via MFMA implicit-GEMM: 4x4x4 tile, halo in LDS, no atomics ----
__global__ __launch_bounds__(256, 4)
void offconv_mfma_kernel(const __half* __restrict__ a1h, const half4_t* __restrict__ wA,
                         float* __restrict__ off) {
    __shared__ __half halo[216 * 52];     // [6x6x6 pos][48 ch + 4 pad], 22.5 KB
    int tid = threadIdx.x;
    int t = blockIdx.x;                    // 0..511 spatial tile
    int b = blockIdx.y;
    int tz0 = (t >> 6) * 4, ty0 = ((t >> 3) & 7) * 4, tx0 = (t & 7) * 4;
    const __half* ab = a1h + (size_t)b * SVOL * CCH;
    for (int idx = tid; idx < 216 * 24; idx += 256) {
        int hpos = idx / 24, kp = idx % 24;
        int hz = hpos / 36, hy = (hpos / 6) % 6, hx = hpos % 6;
        int gz = tz0 + hz - 1, gy = ty0 + hy - 1, gx = tx0 + hx - 1;
        unsigned int v = 0u;
        if (gz >= 0 && gz < 32 && gy >= 0 && gy < 32 && gx >= 0 && gx < 32) {
            int s = (gz * 32 + gy) * 32 + gx;
            v = *reinterpret_cast<const unsigned int*>(ab + (size_t)s * CCH + kp * 2);
        }
        *reinterpret_cast<unsigned int*>(&halo[hpos * 52 + kp * 2]) = v;
    }
    __syncthreads();
    int wave = tid >> 6, lane = tid & 63;
    int col = lane & 15;                   // position col / A row
    int kq = lane >> 4;                    // k-quad 0..3
    int py = col >> 2, px = col & 3;
    int pz = wave;
    float4_t acc[6];
    #pragma unroll
    for (int m = 0; m < 6; m++) acc[m] = (float4_t)0.f;
    for (int tap = 0; tap < 27; tap++) {
        int dz = tap / 9, dy = (tap / 3) % 3, dx = tap % 3;
        int hbase = ((pz + dz) * 36 + (py + dy) * 6 + (px + dx)) * 52 + kq * 4;
        half4_t bf0 = *reinterpret_cast<const half4_t*>(&halo[hbase]);
        half4_t bf1 = *reinterpret_cast<const half4_t*>(&halo[hbase + 16]);
        half4_t bf2 = *reinterpret_cast<const half4_t*>(&halo[hbase + 32]);
        #pragma unroll
        for (int mt = 0; mt < 6; mt++) {
            int fb = (tap * 6 + mt) * 12 + kq;     // f index for ks=0
            half4_t a0 = wA[(size_t)fb * 16 + col];
            half4_t a1 = wA[(size_t)(fb + 4) * 16 + col];
            half4_t a2 = wA[(size_t)(fb + 8) * 16 + col];
            acc[mt] = __builtin_amdgcn_mfma_f32_16x16x16f16(a0, bf0, acc[mt], 0, 0, 0);
            acc[mt] = __builtin_amdgcn_mfma_f32_16x16x16f16(a1, bf1, acc[mt], 0, 0, 0);
            acc[mt] = __builtin_amdgcn_mfma_f32_16x16x16f16(a2, bf2, acc[mt], 0, 0, 0);
        }
    }
    int sg = ((tz0 + pz) * 32 + ty0 + py) * 32 + tx0 + px;
    float* ob = off + (size_t)b * 81 * SVOL + sg;
    #pragma unroll
    for (int mt = 0; mt < 6; mt++) {
        #pragma unroll
        for (int r = 0; r < 4; r++) {
            int orow = mt * 16 + kq * 4 + r;
            if (orow < 81) ob[(size_t)orow * SVOL] = acc[mt][r];
        }
    }
}

// ---- deformable conv 3x3x3: ci-split 3 (16 ch), packed fp16 interp + dot2 matmul ----
struct h8v { half2_t a, b, c, d; };   // 16 bytes = 8 halves

__global__ __launch_bounds__(256, 4)
void deform_kernel(const __half* __restrict__ a1h, const float* __restrict__ off,
                   const float* __restrict__ off_b,
                   const half2_t* __restrict__ wt, float* __restrict__ out) {
    int tid = threadIdx.x;
    int gc = blockIdx.y;            // ci group 0..2 (16 ch = 8 pairs each)
    int b = blockIdx.z;
    int s = blockIdx.x * 256 + tid;
    int z = s >> 10, y = (s >> 5) & 31, xx = s & 31;
    const __half* abase = a1h + (size_t)b * SVOL * CCH + gc * 16;
    const float* ob = off + (size_t)b * 81 * SVOL + s;
    float acc[CCH];
    #pragma unroll
    for (int o = 0; o < CCH; o++) acc[o] = 0.f;
    for (int k = 0; k < 27; k++) {
        int kd = k / 9 - 1, kh = (k / 3) % 3 - 1, kw = k % 3 - 1;
        float zf = (float)(z + kd) + ob[(size_t)(k * 3 + 0) * SVOL] + off_b[k * 3 + 0];
        float yf = (float)(y + kh) + ob[(size_t)(k * 3 + 1) * SVOL] + off_b[k * 3 + 1];
        float xf = (float)(xx + kw) + ob[(size_t)(k * 3 + 2) * SVOL] + off_b[k * 3 + 2];
        float z0 = floorf(zf), y0 = floorf(yf), x0 = floorf(xf);
        float tz = zf - z0, ty = yf - y0, tx = xf - x0;
        int iz0 = (int)z0, iy0 = (int)y0, ix0 = (int)x0;
        half2_t val2[8];
        #pragma unroll
        for (int j = 0; j < 8; j++) val2[j] = (half2_t)(_Float16)0;
        #pragma unroll
        for (int corner = 0; corner < 8; corner++) {
            int dz = corner >> 2, dy = (corner >> 1) & 1, dx = corner & 1;
            int zi = iz0 + dz, yi = iy0 + dy, xi = ix0 + dx;
            bool valid = (zi >= 0 && zi < 32 && yi >= 0 && yi < 32 && xi >= 0 && xi < 32);
            float wgt = (dz ? tz : 1.f - tz) * (dy ? ty : 1.f - ty) * (dx ? tx : 1.f - tx);
            float cwv = valid ? wgt : 0.f;
            _Float16 cwh = (_Float16)cwv;
            half2_t cw2 = { cwh, cwh };
            int zc = min(max(zi, 0), 31), yc = min(max(yi, 0), 31), xc = min(max(xi, 0), 31);
            int cidx = (zc * 32 + yc) * 32 + xc;
            const h8v* pv = (const h8v*)(abase + (size_t)cidx * CCH);
            h8v q0 = pv[0], q1 = pv[1];
            val2[0] += cw2 * q0.a;  val2[1] += cw2 * q0.b;
            val2[2] += cw2 * q0.c;  val2[3] += cw2 * q0.d;
            val2[4] += cw2 * q1.a;  val2[5] += cw2 * q1.b;
            val2[6] += cw2 * q1.c;  val2[7] += cw2 * q1.d;
        }
        #pragma unroll
        for (int cpl = 0; cpl < 8; cpl++) {
            half2_t v2 = val2[cpl];
            const half2_t* wr = wt + ((size_t)k * 24 + gc * 8 + cpl) * CCH;  // uniform
            #pragma unroll
            for (int o = 0; o < CCH; o++) acc[o] = dot2f(v2, wr[o], acc[o]);
        }
    }
    float* op = out + (size_t)b * CCH * SVOL + s;
    #pragma unroll
    for (int o = 0; o < CCH; o++) atomicAdd(&op[(size_t)o * SVOL], acc[o]);
}

// ---- gate1: a2 = (c1 . dc + cb) * u; writes half2-pair a2p ----
__global__ __launch_bounds__(256, 4)
void gate1_kernel(const float* __restrict__ dc, const float* __restrict__ u,
                  const float* __restrict__ wt, const float* __restrict__ cb,
                  half2_t* __restrict__ a2p) {
    int tid = threadIdx.x;
    int g = blockIdx.y, b = blockIdx.z;
    int s = blockIdx.x * 256 + tid;
    size_t base = (size_t)b * CCH * SVOL + s;
    float acc[12];
    #pragma unroll
    for (int o = 0; o < 12; o++) acc[o] = cb[g * 12 + o];
    for (int ci = 0; ci < CCH; ci++) {
        float v = dc[base + (size_t)ci * SVOL];
        const float* wr = wt + ci * CCH + g * 12;
        #pragma unroll
        for (int o = 0; o < 12; o++) acc[o] += wr[o] * v;
    }
    #pragma unroll
    for (int o = 0; o < 12; o++) acc[o] *= u[base + (size_t)(g * 12 + o) * SVOL];
    half2_t* ap = a2p + ((size_t)b * 24 + g * 6) * SVOL + s;
    #pragma unroll
    for (int j = 0; j < 6; j++)
        ap[(size_t)j * SVOL] = half2_t{ (_Float16)acc[2 * j], (_Float16)acc[2 * j + 1] };
}

// ---- gate2: skip = x + gamma*(p2 . a2 + p2b + xn), fp16 dot2; writes fp32 skip + half2 skp ----
__global__ __launch_bounds__(256, 4)
void gate2_kernel(const half2_t* __restrict__ a2p, const float* __restrict__ xn,
                  const float* __restrict__ x,
                  const half2_t* __restrict__ wt, const float* __restrict__ p2b,
                  const float* __restrict__ gamma, float* __restrict__ skip,
                  half2_t* __restrict__ skp) {
    int tid = threadIdx.x;
    int g = blockIdx.y, b = blockIdx.z;
    int s = blockIdx.x * 256 + tid;
    size_t base = (size_t)b * CCH * SVOL + s;
    const half2_t* ab = a2p + (size_t)b * 24 * SVOL + s;
    float acc[12];
    #pragma unroll
    for (int o = 0; o < 12; o++) acc[o] = p2b[g * 12 + o];
    for (int cp = 0; cp < 24; cp++) {
        half2_t v2 = ab[(size_t)cp * SVOL];
        const half2_t* wr = wt + cp * CCH + g * 12;
        #pragma unroll
        for (int o = 0; o < 12; o++) acc[o] = dot2f(v2, wr[o], acc[o]);
    }
    float sv[12];
    #pragma unroll
    for (int o = 0; o < 12; o++) {
        int oc = g * 12 + o;
        float vv = acc[o] + xn[base + (size_t)oc * SVOL];
        sv[o] = x[base + (size_t)oc * SVOL] + gamma[oc] * vv;
        skip[base + (size_t)oc * SVOL] = sv[o];
    }
    half2_t* sp = skp + ((size_t)b * 24 + g * 6) * SVOL + s;
    #pragma unroll
    for (int j = 0; j < 6; j++)
        sp[(size_t)j * SVOL] = half2_t{ (_Float16)sv[2 * j], (_Float16)sv[2 * j + 1] };
}

// ---- u1: 3x3x3 conv + BN1 + LeakyReLU, fp16 dot2; writes packed half2 output ----
__global__ __launch_bounds__(256, 4)
void u1_kernel(const half2_t* __restrict__ skp, const half2_t* __restrict__ wt,
               const float* __restrict__ bs, const float* __restrict__ bb,
               const float* __restrict__ bm, const float* __restrict__ bv,
               half2_t* __restrict__ h1p) {
    int tid = threadIdx.x;
    int g = blockIdx.y, b = blockIdx.z;
    int s = blockIdx.x * 256 + tid;
    int z = s >> 10, y = (s >> 5) & 31, xx = s & 31;
    const half2_t* ib = skp + (size_t)b * 24 * SVOL;
    float acc[12];
    #pragma unroll
    for (int o = 0; o < 12; o++) acc[o] = 0.f;
    for (int tap = 0; tap < 27; tap++) {
        int dz = tap / 9 - 1, dy = (tap / 3) % 3 - 1, dx = tap % 3 - 1;
        int zz = z + dz, yy = y + dy, xv = xx + dx;
        bool ok = (zz >= 0 && zz < 32 && yy >= 0 && yy < 32 && xv >= 0 && xv < 32);
        if (ok) {
            int si = (zz * 32 + yy) * 32 + xv;
            for (int cp = 0; cp < 24; cp++) {
                half2_t v2 = ib[(size_t)cp * SVOL + si];
                const half2_t* wr = wt + ((size_t)tap * 24 + cp) * CCH + g * 12;  // uniform
                #pragma unroll
                for (int o = 0; o < 12; o++) acc[o] = dot2f(v2, wr[o], acc[o]);
            }
        }
    }
    float hv[12];
    #pragma unroll
    for (int o = 0; o < 12; o++) {
        int oc = g * 12 + o;
        float inv = rsqrtf(bv[oc] + 1e-5f);
        float h = (acc[o] - bm[oc]) * (bs[oc] * inv) + bb[oc];
        hv[o] = h >= 0.f ? h : 0.01f * h;
    }
    half2_t* op = h1p + ((size_t)b * 24 + g * 6) * SVOL + s;
    #pragma unroll
    for (int j = 0; j < 6; j++)
        op[(size_t)j * SVOL] = half2_t{ (_Float16)hv[2 * j], (_Float16)hv[2 * j + 1] };
}

// ---- u2_bn: 3x3x3 conv (fp16 dot2) + BN2 + (+skip fp32) + LeakyReLU -> attnp half2 ----
__global__ __launch_bounds__(256, 4)
void u2_bn_kernel(const half2_t* __restrict__ h1p, const float* __restrict__ skip,
                  const half2_t* __restrict__ wt,
                  const float* __restrict__ bs, const float* __restrict__ bb,
                  const float* __restrict__ bm, const float* __restrict__ bv,
                  half2_t* __restrict__ attnp) {
    int tid = threadIdx.x;
    int g = blockIdx.y, b = blockIdx.z;
    int s = blockIdx.x * 256 + tid;
    int z = s >> 10, y = (s >> 5) & 31, xx = s & 31;
    const half2_t* ib = h1p + (size_t)b * 24 * SVOL;
    float acc[12];
    #pragma unroll
    for (int o = 0; o < 12; o++) acc[o] = 0.f;
    for (int tap = 0; tap < 27; tap++) {
        int dz = tap / 9 - 1, dy = (tap / 3) % 3 - 1, dx = tap % 3 - 1;
        int zz = z + dz, yy = y + dy, xv = xx + dx;
        bool ok = (zz >= 0 && zz < 32 && yy >= 0 && yy < 32 && xv >= 0 && xv < 32);
        if (ok) {
            int si = (zz * 32 + yy) * 32 + xv;
            for (int cp = 0; cp < 24; cp++) {
                half2_t v2 = ib[(size_t)cp * SVOL + si];
                const half2_t* wr = wt + ((size_t)tap * 24 + cp) * CCH + g * 12;  // uniform
                #pragma unroll
                for (int o = 0; o < 12; o++) acc[o] = dot2f(v2, wr[o], acc[o]);
            }
        }
    }
    size_t base = (size_t)b * CCH * SVOL + s;
    float av[12];
    #pragma unroll
    for (int o = 0; o < 12; o++) {
        int oc = g * 12 + o;
        float inv = rsqrtf(bv[oc] + 1e-5f);
        float h = (acc[o] - bm[oc]) * (bs[oc] * inv) + bb[oc];
        float a = h + skip[base + (size_t)oc * SVOL];
        av[o] = a >= 0.f ? a : 0.01f * a;
    }
    half2_t* op = attnp + ((size_t)b * 24 + g * 6) * SVOL + s;
    #pragma unroll
    for (int j = 0; j < 6; j++)
        op[(size_t)j * SVOL] = half2_t{ (_Float16)av[2 * j], (_Float16)av[2 * j + 1] };
}

// ---- pr_final: out = skip + pr(attn), fp16 dot2 ----
__global__ __launch_bounds__(256, 4)
void pr_final_kernel(const half2_t* __restrict__ attnp, const float* __restrict__ skip,
                     const half2_t* __restrict__ wt, const float* __restrict__ prb,
                     float* __restrict__ out) {
    int tid = threadIdx.x;
    int g = blockIdx.y, b = blockIdx.z;
    int s = blockIdx.x * 256 + tid;
    size_t base = (size_t)b * CCH * SVOL + s;
    const half2_t* ab = attnp + (size_t)b * 24 * SVOL + s;
    float acc[12];
    #pragma unroll
    for (int o = 0; o < 12; o++) acc[o] = prb[g * 12 + o];
    for (int cp = 0; cp < 24; cp++) {
        half2_t v2 = ab[(size_t)cp * SVOL];
        const half2_t* wr = wt + cp * CCH + g * 12;
        #pragma unroll
        for (int o = 0; o < 12; o++) acc[o] = dot2f(v2, wr[o], acc[o]);
    }
    #pragma unroll
    for (int o = 0; o < 12; o++) {
        int oc = g * 12 + o;
        out[base + (size_t)oc * SVOL] = skip[base + (size_t)oc * SVOL] + acc[o];
    }
}

extern "C" void kernel_launch(void* const* d_in, const int* in_sizes, int n_in,
                              void* d_out, int out_size, void* d_ws, size_t ws_size,
                              hipStream_t stream) {
    (void)in_sizes; (void)n_in; (void)out_size; (void)ws_size;
    const float* x     = (const float*)d_in[0];
    const float* ln_s  = (const float*)d_in[1];
    const float* ln_b  = (const float*)d_in[2];
    const float* gamma = (const float*)d_in[3];
    const float* p1_w  = (const float*)d_in[4];
    const float* p1_b  = (const float*)d_in[5];
    const float* p2_w  = (const float*)d_in[6];
    const float* p2_b  = (const float*)d_in[7];
    const float* c0_w  = (const float*)d_in[8];
    const float* c0_b  = (const float*)d_in[9];
    const float* cs_w  = (const float*)d_in[10];
    const float* cs_b  = (const float*)d_in[11];
    const float* off_w = (const float*)d_in[12];
    const float* off_b = (const float*)d_in[13];
    const float* dc_w  = (const float*)d_in[14];
    const float* dc_b  = (const float*)d_in[15];
    const float* c1_w  = (const float*)d_in[16];
    const float* c1_b  = (const float*)d_in[17];
    const float* u1_w  = (const float*)d_in[18];
    const float* bn1_s = (const float*)d_in[19];
    const float* bn1_b = (const float*)d_in[20];
    const float* bn1_m = (const float*)d_in[21];
    const float* bn1_v = (const float*)d_in[22];
    const float* u2_w  = (const float*)d_in[23];
    const float* bn2_s = (const float*)d_in[24];
    const float* bn2_b = (const float*)d_in[25];
    const float* bn2_m = (const float*)d_in[26];
    const float* bn2_v = (const float*)d_in[27];
    const float* pr_w  = (const float*)d_in[28];
    const float* pr_b  = (const float*)d_in[29];
    float* out = (float*)d_out;

    float* wsf = (float*)d_ws;
    const size_t TS = (size_t)NB * CCH * SVOL;   // 3,145,728 floats
    float* xn   = out;            // d_out doubles as xn fp32 (dead after gate2)
    float* ubuf = wsf;            // u (gelu out fp32) -> [skp | h1p] (half2)
    float* bufA = wsf + TS;       // dw5 out -> a1h -> skip (fp32)
    float* bufB = wsf + 2 * TS;   // xnp (half2) -> dw7 out (a1) -> deform partials (dc)
    float* offb = wsf + 3 * TS;   // offsets [B,81,S] -> a2p (half2) -> attnp (half2)
    float* wtb    = wsf + 3 * TS + (size_t)NB * 81 * SVOL;
    float* wt_offf = wtb;                   // MFMA A frags: 31104 half4 = 62208 floats
    float* wt_dcf  = wt_offf + 104976;
    float* wt_u1f  = wt_dcf + 62208;
    float* wt_u2f  = wt_u1f + 62208;
    float* pt_p1  = wt_u2f + 62208;
    float* pt_c1  = pt_p1 + 2304;
    float* pt_p2  = pt_c1 + 2304;
    float* pt_pr  = pt_p2 + 2304;
    float* cb_all = pt_pr + 2304;

    __half*  a1h = (__half*)bufA;
    half2_t* skp = (half2_t*)ubuf;
    half2_t* h1p = (half2_t*)(ubuf + TS / 2);
    half2_t* xnp = (half2_t*)bufB;
    half2_t* a2p = (half2_t*)offb;
    half2_t* attnp = (half2_t*)offb;
    half4_t* wA_off = (half4_t*)wt_offf;
    half2_t* wt_dch  = (half2_t*)wt_dcf;
    half2_t* wt_u1h  = (half2_t*)wt_u1f;
    half2_t* wt_u2h  = (half2_t*)wt_u2f;
    half2_t* wt_p1h  = (half2_t*)pt_p1;
    half2_t* wt_p2h  = (half2_t*)pt_p2;
    half2_t* wt_prh  = (half2_t*)pt_pr;

    dim3 blk(256);
    dim3 gpos(SVOL / 256, NB);
    dim3 g4(SVOL / 256, 4, NB);
    dim3 gmf(512, NB);                 // offconv MFMA: 8x8x8 spatial tiles
    dim3 g3d(SVOL / 256, 3, NB);
    dim3 gdwc(8, CCH, NB);
    dim3 gtr(SVOL / 64, NB);

    hipLaunchKernelGGL(reshape_mfma_off_kernel, dim3((31104 + 255) / 256), blk, 0, stream, off_w, wA_off);
    hipLaunchKernelGGL(reshape_pair_kernel, dim3((27 * 24 * 48 + 255) / 256), blk, 0, stream, dc_w,  wt_dch,  48);
    hipLaunchKernelGGL(reshape_pair_kernel, dim3((27 * 24 * 48 + 255) / 256), blk, 0, stream, u1_w,  wt_u1h,  48);
    hipLaunchKernelGGL(reshape_pair_kernel, dim3((27 * 24 * 48 + 255) / 256), blk, 0, stream, u2_w,  wt_u2h,  48);
    hipLaunchKernelGGL(t1x1_pair_kernel, dim3(5), blk, 0, stream, p1_w, wt_p1h);
    hipLaunchKernelGGL(t1x1_pair_kernel, dim3(5), blk, 0, stream, p2_w, wt_p2h);
    hipLaunchKernelGGL(t1x1_pair_kernel, dim3(5), blk, 0, stream, pr_w, wt_prh);
    hipLaunchKernelGGL(t1x1_kernel, dim3(9), blk, 0, stream, c1_w, pt_c1);
    hipLaunchKernelGGL(cb_kernel, dim3(1), dim3(64), 0, stream, c1_w, c1_b, dc_b, cb_all);

    hipLaunchKernelGGL(ln_kernel,            gpos, blk, 0, stream, x, ln_s, ln_b, xn, xnp);
    hipLaunchKernelGGL(p1_gelu_kernel,       g4,   blk, 0, stream, xnp, wt_p1h, p1_b, ubuf);
    hipLaunchKernelGGL(dw5_kernel,           gdwc, blk, 0, stream, ubuf, c0_w, c0_b, bufA);
    hipLaunchKernelGGL(dw7_kernel,           gdwc, blk, 0, stream, bufA, cs_w, cs_b, bufB);
    hipLaunchKernelGGL(transpose_pack_kernel, gtr, blk, 0, stream, bufB, a1h);
    hipLaunchKernelGGL(offconv_mfma_kernel,  gmf,  blk, 0, stream, a1h, wA_off, offb);
    hipMemsetAsync(bufB, 0, TS * sizeof(float), stream);
    hipLaunchKernelGGL(deform_kernel,        g3d,  blk, 0, stream, a1h, offb, off_b, wt_dch, bufB);
    hipLaunchKernelGGL(gate1_kernel,         g4,   blk, 0, stream, bufB, ubuf, pt_c1, cb_all, a2p);
    hipLaunchKernelGGL(gate2_kernel,         g4,   blk, 0, stream, a2p, xn, x, wt_p2h, p2_b, gamma,
                       bufA, skp);
    hipLaunchKernelGGL(u1_kernel,            g4,   blk, 0, stream, skp, wt_u1h,
                       bn1_s, bn1_b, bn1_m, bn1_v, h1p);
    hipLaunchKernelGGL(u2_bn_kernel,         g4,   blk, 0, stream, h1p, bufA, wt_u2h,
                       bn2_s, bn2_b, bn2_m, bn2_v, attnp);
    hipLaunchKernelGGL(pr_final_kernel,      g4,   blk, 0, stream, attnp, bufA, wt_prh, pr_b, out);
}

// Round 25
// 504.538 us; speedup vs baseline: 1.2150x; 1.2107x over previous
//
#include <hip/hip_runtime.h>
#include <hip/hip_fp16.h>
#include <math.h>

#define CCH 48
#define SDIM 32
#define SVOL (SDIM*SDIM*SDIM)
#define NB 2

typedef _Float16 half2_t __attribute__((ext_vector_type(2)));
typedef _Float16 half4_t __attribute__((ext_vector_type(4)));
typedef float float4_t __attribute__((ext_vector_type(4)));

static __device__ __forceinline__ float dot2f(half2_t a, half2_t b, float c) {
#if __has_builtin(__builtin_amdgcn_fdot2)
    return __builtin_amdgcn_fdot2(a, b, c, false);
#else
    return c + (float)a[0] * (float)b[0] + (float)a[1] * (float)b[1];
#endif
}

// ======== one-off weight reshape kernels ========

__global__ __launch_bounds__(256)
void reshape_pair_kernel(const float* __restrict__ w, half2_t* __restrict__ wt, int NO) {
    int i = blockIdx.x * 256 + threadIdx.x;
    int total = 27 * 24 * NO;
    if (i < total) {
        int o = i % NO; int rem = i / NO; int cp = rem % 24; int k = rem / 24;
        float w0 = w[((size_t)o * CCH + 2 * cp) * 27 + k];
        float w1 = w[((size_t)o * CCH + 2 * cp + 1) * 27 + k];
        wt[i] = half2_t{ (_Float16)w0, (_Float16)w1 };
    }
}

// off_w[81][48][27] -> MFMA A-fragments: e = (((tap*6+mt)*3+ks)*4+kq)*16+row, rows 81..95 zero.
__global__ __launch_bounds__(256)
void reshape_mfma_off_kernel(const float* __restrict__ w, half4_t* __restrict__ wA) {
    int e = blockIdx.x * 256 + threadIdx.x;
    if (e < 31104) {
        int row = e & 15;
        int kq = (e >> 4) & 3;
        int ks = (e / 64) % 3;
        int mt = (e / 192) % 6;
        int tap = e / 1152;
        int o = mt * 16 + row;
        half4_t v;
        #pragma unroll
        for (int h = 0; h < 4; h++) {
            int ci = ks * 16 + kq * 4 + h;
            float val = (o < 81) ? w[((size_t)o * CCH + ci) * 27 + tap] : 0.f;
            v[h] = (_Float16)val;
        }
        wA[e] = v;
    }
}

// w[48][48][27] -> MFMA A-fragments (M=48, 3 mt): e = (((tap*3+mt)*3+ks)*4+kq)*16+row
__global__ __launch_bounds__(256)
void reshape_mfma48_kernel(const float* __restrict__ w, half4_t* __restrict__ wA) {
    int e = blockIdx.x * 256 + threadIdx.x;
    if (e < 15552) {
        int row = e & 15;
        int kq = (e >> 4) & 3;
        int ks = (e / 64) % 3;
        int mt = (e / 192) % 3;
        int tap = e / 576;
        int o = mt * 16 + row;
        half4_t v;
        #pragma unroll
        for (int h = 0; h < 4; h++) {
            int ci = ks * 16 + kq * 4 + h;
            v[h] = (_Float16)w[((size_t)o * CCH + ci) * 27 + tap];
        }
        wA[e] = v;
    }
}

__global__ __launch_bounds__(256)
void t1x1_pair_kernel(const float* __restrict__ w, half2_t* __restrict__ wt) {
    int i = blockIdx.x * 256 + threadIdx.x;
    if (i < 24 * CCH) {
        int o = i % CCH, cp = i / CCH;
        wt[i] = half2_t{ (_Float16)w[o * CCH + 2 * cp], (_Float16)w[o * CCH + 2 * cp + 1] };
    }
}

__global__ __launch_bounds__(256)
void t1x1_kernel(const float* __restrict__ w, float* __restrict__ wt) {
    int i = blockIdx.x * 256 + threadIdx.x;
    if (i < CCH * CCH) { int ci = i / CCH, o = i % CCH; wt[i] = w[o * CCH + ci]; }
}

__global__ __launch_bounds__(64)
void cb_kernel(const float* __restrict__ c1w, const float* __restrict__ c1b,
               const float* __restrict__ dcb, float* __restrict__ cb) {
    int o = threadIdx.x;
    if (o < CCH) {
        float v = c1b[o];
        for (int ci = 0; ci < CCH; ci++) v += c1w[o * CCH + ci] * dcb[ci];
        cb[o] = v;
    }
}

// ---------------- LayerNorm over C; writes fp32 xn AND half2-pair xnp ----------------
__global__ __launch_bounds__(256)
void ln_kernel(const float* __restrict__ x, const float* __restrict__ ln_s,
               const float* __restrict__ ln_b, float* __restrict__ xn,
               half2_t* __restrict__ xnp) {
    int s = blockIdx.x * 256 + threadIdx.x;
    int b = blockIdx.y;
    const float* xb = x + (size_t)b * CCH * SVOL + s;
    float v[CCH];
    float mu = 0.f;
    #pragma unroll
    for (int c = 0; c < CCH; c++) { v[c] = xb[c * SVOL]; mu += v[c]; }
    mu *= (1.0f / CCH);
    float var = 0.f;
    #pragma unroll
    for (int c = 0; c < CCH; c++) { float d = v[c] - mu; var += d * d; }
    var *= (1.0f / CCH);
    float inv = rsqrtf(var + 1e-5f);
    float* o = xn + (size_t)b * CCH * SVOL + s;
    float nv[CCH];
    #pragma unroll
    for (int c = 0; c < CCH; c++) { nv[c] = (v[c] - mu) * inv * ln_s[c] + ln_b[c]; o[c * SVOL] = nv[c]; }
    half2_t* xp = xnp + (size_t)b * 24 * SVOL + s;
    #pragma unroll
    for (int cp = 0; cp < 24; cp++)
        xp[(size_t)cp * SVOL] = half2_t{ (_Float16)nv[2 * cp], (_Float16)nv[2 * cp + 1] };
}

// ---------------- 1x1x1 conv + exact GELU (4 groups x 12), fp16 dot2 ----------------
__global__ __launch_bounds__(256, 4)
void p1_gelu_kernel(const half2_t* __restrict__ xnp, const half2_t* __restrict__ wt,
                    const float* __restrict__ bias, float* __restrict__ u) {
    int tid = threadIdx.x;
    int g = blockIdx.y, b = blockIdx.z;
    int s = blockIdx.x * 256 + tid;
    const half2_t* xb = xnp + (size_t)b * 24 * SVOL + s;
    float acc[12];
    #pragma unroll
    for (int o = 0; o < 12; o++) acc[o] = bias[g * 12 + o];
    for (int cp = 0; cp < 24; cp++) {
        half2_t v2 = xb[(size_t)cp * SVOL];
        const half2_t* wr = wt + cp * CCH + g * 12;
        #pragma unroll
        for (int o = 0; o < 12; o++) acc[o] = dot2f(v2, wr[o], acc[o]);
    }
    float* ub = u + (size_t)b * CCH * SVOL + s + (size_t)(g * 12) * SVOL;
    #pragma unroll
    for (int o = 0; o < 12; o++) {
        float a = acc[o];
        ub[o * SVOL] = 0.5f * a * (1.0f + erff(a * 0.70710678118654752f));
    }
}

// ---- depthwise 5x5x5 pad 2: half-column blocking (16 z/thread, window cache) ----
__global__ __launch_bounds__(256, 4)
void dw5_kernel(const float* __restrict__ in, const float* __restrict__ w,
                const float* __restrict__ bias, float* __restrict__ out) {
    int tid = threadIdx.x;
    int c = blockIdx.y, b = blockIdx.z;
    const float* wc = w + c * 125;
    int bx = blockIdx.x;
    int yx = (bx >> 1) * 256 + tid;
    int z0 = (bx & 1) * 16;
    int y = yx >> 5, xx = yx & 31;
    const float* ib = in + ((size_t)b * CCH + c) * SVOL;
    float acc[16];
    float bv = bias[c];
    #pragma unroll
    for (int z = 0; z < 16; z++) acc[z] = bv;
    for (int ty = 0; ty < 5; ty++) {
        int yy = y + ty - 2; if (yy < 0 || yy >= 32) continue;
        for (int tx = 0; tx < 5; tx++) {
            int xv = xx + tx - 2; if (xv < 0 || xv >= 32) continue;
            const float* col = ib + yy * 32 + xv;
            float cv[20];
            #pragma unroll
            for (int j = 0; j < 20; j++) {
                int zz = z0 - 2 + j;
                cv[j] = (zz >= 0 && zz < 32) ? col[(size_t)zz * 1024] : 0.f;
            }
            #pragma unroll
            for (int tz = 0; tz < 5; tz++) {
                float wv = wc[(tz * 5 + ty) * 5 + tx];
                #pragma unroll
                for (int z = 0; z < 16; z++) acc[z] += wv * cv[z + tz];
            }
        }
    }
    float* ob = out + ((size_t)b * CCH + c) * SVOL + y * 32 + xx;
    #pragma unroll
    for (int z = 0; z < 16; z++) ob[(size_t)(z0 + z) * 1024] = acc[z];
}

// ---- depthwise 7x7x7 dil 3 pad 9: half-column blocking (16 z/thread, window cache) ----
__global__ __launch_bounds__(256, 4)
void dw7_kernel(const float* __restrict__ in, const float* __restrict__ w,
                const float* __restrict__ bias, float* __restrict__ out) {
    int tid = threadIdx.x;
    int c = blockIdx.y, b = blockIdx.z;
    const float* wc = w + c * 343;
    int bx = blockIdx.x;
    int yx = (bx >> 1) * 256 + tid;
    int z0 = (bx & 1) * 16;
    int y = yx >> 5, xx = yx & 31;
    const float* ib = in + ((size_t)b * CCH + c) * SVOL;
    float acc[16];
    float bv = bias[c];
    #pragma unroll
    for (int z = 0; z < 16; z++) acc[z] = bv;
    for (int ty = 0; ty < 7; ty++) {
        int yy = y + 3 * (ty - 3); if (yy < 0 || yy >= 32) continue;
        for (int tx = 0; tx < 7; tx++) {
            int xv = xx + 3 * (tx - 3); if (xv < 0 || xv >= 32) continue;
            const float* col = ib + yy * 32 + xv;
            float cv[34];
            #pragma unroll
            for (int j = 0; j < 34; j++) {
                int zz = z0 - 9 + j;
                cv[j] = (zz >= 0 && zz < 32) ? col[(size_t)zz * 1024] : 0.f;
            }
            #pragma unroll
            for (int tz = 0; tz < 7; tz++) {
                float wv = wc[(tz * 7 + ty) * 7 + tx];
                #pragma unroll
                for (int z = 0; z < 16; z++) acc[z] += wv * cv[z + 3 * tz];
            }
        }
    }
    float* ob = out + ((size_t)b * CCH + c) * SVOL + y * 32 + xx;
    #pragma unroll
    for (int z = 0; z < 16; z++) ob[(size_t)(z0 + z) * 1024] = acc[z];
}

// ---- a1 fp32 [48][S] -> a1h fp16 [S][48] ----
__global__ __launch_bounds__(256)
void transpose_pack_kernel(const float* __restrict__ a1, __half* __restrict__ a1h) {
    __shared__ float tile[CCH * 65];
    int tid = threadIdx.x;
    int b = blockIdx.y;
    int s0 = blockIdx.x * 64;
    const float* ib = a1 + (size_t)b * CCH * SVOL + s0;
    for (int i = tid; i < CCH * 64; i += 256) {
        int c = i >> 6, p = i & 63;
        tile[c * 65 + p] = ib[(size_t)c * SVOL + p];
    }
    __syncthreads();
    __half* ob = a1h + ((size_t)b * SVOL + s0) * CCH;
    for (int i = tid; i < 64 * CCH; i += 256) {
        int p = i / CCH, c = i % CCH;
        ob[i] = __float2half(tile[c * 65 + p]);
    }
}

// ---- offset conv 3x3x3 via MFMA implicit-GEMM: 4x4x4 tile, halo in LDS, no atomics ----
__global__ __launch_bounds__(256, 4)
void offconv_mfma_kernel(const __half* __restrict__ a1h, const half4_t* __restrict__ wA,
                         float* __restrict__ off) {
    __shared__ __half halo[216 * 52];
    int tid = threadIdx.x;
    int t = blockIdx.x;
    int b = blockIdx.y;
    int tz0 = (t >> 6) * 4, ty0 = ((t >> 3) & 7) * 4, tx0 = (t & 7) * 4;
    const __half* ab = a1h + (size_t)b * SVOL * CCH;
    for (int idx = tid; idx < 216 * 24; idx += 256) {
        int hpos = idx / 24, kp = idx % 24;
        int hz = hpos / 36, hy = (hpos / 6) % 6, hx = hpos % 6;
        int gz = tz0 + hz - 1, gy = ty0 + hy - 1, gx = tx0 + hx - 1;
        unsigned int v = 0u;
        if (gz >= 0 && gz < 32 && gy >= 0 && gy < 32 && gx >= 0 && gx < 32) {
            int s = (gz * 32 + gy) * 32 + gx;
            v = *reinterpret_cast<const unsigned int*>(ab + (size_t)s * CCH + kp * 2);
        }
        *reinterpret_cast<unsigned int*>(&halo[hpos * 52 + kp * 2]) = v;
    }
    __syncthreads();
    int wave = tid >> 6, lane = tid & 63;
    int col = lane & 15;
    int kq = lane >> 4;
    int py = col >> 2, px = col & 3;
    int pz = wave;
    float4_t acc[6];
    #pragma unroll
    for (int m = 0; m < 6; m++) acc[m] = (float4_t)0.f;
    for (int tap = 0; tap < 27; tap++) {
        int dz = tap / 9, dy = (tap / 3) % 3, dx = tap % 3;
        int hbase = ((pz + dz) * 36 + (py + dy) * 6 + (px + dx)) * 52 + kq * 4;
        half4_t bf0 = *reinterpret_cast<const half4_t*>(&halo[hbase]);
        half4_t bf1 = *reinterpret_cast<const half4_t*>(&halo[hbase + 16]);
        half4_t bf2 = *reinterpret_cast<const half4_t*>(&halo[hbase + 32]);
        #pragma unroll
        for (int mt = 0; mt < 6; mt++) {
            int fb = (tap * 6 + mt) * 12 + kq;
            half4_t a0 = wA[(size_t)fb * 16 + col];
            half4_t a1 = wA[(size_t)(fb + 4) * 16 + col];
            half4_t a2 = wA[(size_t)(fb + 8) * 16 + col];
            acc[mt] = __builtin_amdgcn_mfma_f32_16x16x16f16(a0, bf0, acc[mt], 0, 0, 0);
            acc[mt] = __builtin_amdgcn_mfma_f32_16x16x16f16(a1, bf1, acc[mt], 0, 0, 0);
            acc[mt] = __builtin_amdgcn_mfma_f32_16x16x16f16(a2, bf2, acc[mt], 0, 0, 0);
        }
    }
    int sg = ((tz0 + pz) * 32 + ty0 + py) * 32 + tx0 + px;
    float* ob = off + (size_t)b * 81 * SVOL + sg;
    #pragma unroll
    for (int mt = 0; mt < 6; mt++) {
        #pragma unroll
        for (int r = 0; r < 4; r++) {
            int orow = mt * 16 + kq * 4 + r;
            if (orow < 81) ob[(size_t)orow * SVOL] = acc[mt][r];
        }
    }
}

// ---- u1 3x3x3 via MFMA + BN1 + LeakyReLU; in: skh [S][48] fp16, out: h1h [S][48] fp16 ----
__global__ __launch_bounds__(256, 4)
void u1_mfma_kernel(const __half* __restrict__ skh, const half4_t* __restrict__ wA,
                    const float* __restrict__ bs, const float* __restrict__ bb,
                    const float* __restrict__ bm, const float* __restrict__ bv,
                    __half* __restrict__ h1h) {
    __shared__ __half halo[216 * 52];
    int tid = threadIdx.x;
    int t = blockIdx.x;
    int b = blockIdx.y;
    int tz0 = (t >> 6) * 4, ty0 = ((t >> 3) & 7) * 4, tx0 = (t & 7) * 4;
    const __half* ab = skh + (size_t)b * SVOL * CCH;
    for (int idx = tid; idx < 216 * 24; idx += 256) {
        int hpos = idx / 24, kp = idx % 24;
        int hz = hpos / 36, hy = (hpos / 6) % 6, hx = hpos % 6;
        int gz = tz0 + hz - 1, gy = ty0 + hy - 1, gx = tx0 + hx - 1;
        unsigned int v = 0u;
        if (gz >= 0 && gz < 32 && gy >= 0 && gy < 32 && gx >= 0 && gx < 32) {
            int s = (gz * 32 + gy) * 32 + gx;
            v = *reinterpret_cast<const unsigned int*>(ab + (size_t)s * CCH + kp * 2);
        }
        *reinterpret_cast<unsigned int*>(&halo[hpos * 52 + kp * 2]) = v;
    }
    __syncthreads();
    int wave = tid >> 6, lane = tid & 63;
    int col = lane & 15;
    int kq = lane >> 4;
    int py = col >> 2, px = col & 3;
    int pz = wave;
    float4_t acc[3];
    #pragma unroll
    for (int m = 0; m < 3; m++) acc[m] = (float4_t)0.f;
    for (int tap = 0; tap < 27; tap++) {
        int dz = tap / 9, dy = (tap / 3) % 3, dx = tap % 3;
        int hbase = ((pz + dz) * 36 + (py + dy) * 6 + (px + dx)) * 52 + kq * 4;
        half4_t bf0 = *reinterpret_cast<const half4_t*>(&halo[hbase]);
        half4_t bf1 = *reinterpret_cast<const half4_t*>(&halo[hbase + 16]);
        half4_t bf2 = *reinterpret_cast<const half4_t*>(&halo[hbase + 32]);
        #pragma unroll
        for (int mt = 0; mt < 3; mt++) {
            int fb = (tap * 3 + mt) * 12 + kq;
            half4_t a0 = wA[(size_t)fb * 16 + col];
            half4_t a1 = wA[(size_t)(fb + 4) * 16 + col];
            half4_t a2 = wA[(size_t)(fb + 8) * 16 + col];
            acc[mt] = __builtin_amdgcn_mfma_f32_16x16x16f16(a0, bf0, acc[mt], 0, 0, 0);
            acc[mt] = __builtin_amdgcn_mfma_f32_16x16x16f16(a1, bf1, acc[mt], 0, 0, 0);
            acc[mt] = __builtin_amdgcn_mfma_f32_16x16x16f16(a2, bf2, acc[mt], 0, 0, 0);
        }
    }
    int sg = ((tz0 + pz) * 32 + ty0 + py) * 32 + tx0 + px;
    __half* ob = h1h + ((size_t)b * SVOL + sg) * CCH;
    #pragma unroll
    for (int mt = 0; mt < 3; mt++) {
        float hv[4];
        #pragma unroll
        for (int r = 0; r < 4; r++) {
            int orow = mt * 16 + kq * 4 + r;
            float inv = rsqrtf(bv[orow] + 1e-5f);
            float h = (acc[mt][r] - bm[orow]) * (bs[orow] * inv) + bb[orow];
            hv[r] = h >= 0.f ? h : 0.01f * h;
        }
        half2_t* po = reinterpret_cast<half2_t*>(ob + mt * 16 + kq * 4);
        po[0] = half2_t{ (_Float16)hv[0], (_Float16)hv[1] };
        po[1] = half2_t{ (_Float16)hv[2], (_Float16)hv[3] };
    }
}

// ---- u2 3x3x3 via MFMA + BN2 + (+skip fp32) + LeakyReLU; out: attnh [S][48] fp16 ----
__global__ __launch_bounds__(256, 4)
void u2_mfma_kernel(const __half* __restrict__ h1h, const float* __restrict__ skip,
                    const half4_t* __restrict__ wA,
                    const float* __restrict__ bs, const float* __restrict__ bb,
                    const float* __restrict__ bm, const float* __restrict__ bv,
                    __half* __restrict__ attnh) {
    __shared__ __half halo[216 * 52];
    int tid = threadIdx.x;
    int t = blockIdx.x;
    int b = blockIdx.y;
    int tz0 = (t >> 6) * 4, ty0 = ((t >> 3) & 7) * 4, tx0 = (t & 7) * 4;
    const __half* ab = h1h + (size_t)b * SVOL * CCH;
    for (int idx = tid; idx < 216 * 24; idx += 256) {
        int hpos = idx / 24, kp = idx % 24;
        int hz = hpos / 36, hy = (hpos / 6) % 6, hx = hpos % 6;
        int gz = tz0 + hz - 1, gy = ty0 + hy - 1, gx = tx0 + hx - 1;
        unsigned int v = 0u;
        if (gz >= 0 && gz < 32 && gy >= 0 && gy < 32 && gx >= 0 && gx < 32) {
            int s = (gz * 32 + gy) * 32 + gx;
            v = *reinterpret_cast<const unsigned int*>(ab + (size_t)s * CCH + kp * 2);
        }
        *reinterpret_cast<unsigned int*>(&halo[hpos * 52 + kp * 2]) = v;
    }
    __syncthreads();
    int wave = tid >> 6, lane = tid & 63;
    int col = lane & 15;
    int kq = lane >> 4;
    int py = col >> 2, px = col & 3;
    int pz = wave;
    float4_t acc[3];
    #pragma unroll
    for (int m = 0; m < 3; m++) acc[m] = (float4_t)0.f;
    for (int tap = 0; tap < 27; tap++) {
        int dz = tap / 9, dy = (tap / 3) % 3, dx = tap % 3;
        int hbase = ((pz + dz) * 36 + (py + dy) * 6 + (px + dx)) * 52 + kq * 4;
        half4_t bf0 = *reinterpret_cast<const half4_t*>(&halo[hbase]);
        half4_t bf1 = *reinterpret_cast<const half4_t*>(&halo[hbase + 16]);
        half4_t bf2 = *reinterpret_cast<const half4_t*>(&halo[hbase + 32]);
        #pragma unroll
        for (int mt = 0; mt < 3; mt++) {
            int fb = (tap * 3 + mt) * 12 + kq;
            half4_t a0 = wA[(size_t)fb * 16 + col];
            half4_t a1 = wA[(size_t)(fb + 4) * 16 + col];
            half4_t a2 = wA[(size_t)(fb + 8) * 16 + col];
            acc[mt] = __builtin_amdgcn_mfma_f32_16x16x16f16(a0, bf0, acc[mt], 0, 0, 0);
            acc[mt] = __builtin_amdgcn_mfma_f32_16x16x16f16(a1, bf1, acc[mt], 0, 0, 0);
            acc[mt] = __builtin_amdgcn_mfma_f32_16x16x16f16(a2, bf2, acc[mt], 0, 0, 0);
        }
    }
    int sg = ((tz0 + pz) * 32 + ty0 + py) * 32 + tx0 + px;
    const float* sk = skip + (size_t)b * CCH * SVOL + sg;
    __half* ob = attnh + ((size_t)b * SVOL + sg) * CCH;
    #pragma unroll
    for (int mt = 0; mt < 3; mt++) {
        float av[4];
        #pragma unroll
        for (int r = 0; r < 4; r++) {
            int orow = mt * 16 + kq * 4 + r;
            float inv = rsqrtf(bv[orow] + 1e-5f);
            float h = (acc[mt][r] - bm[orow]) * (bs[orow] * inv) + bb[orow];
            float a = h + sk[(size_t)orow * SVOL];
            av[r] = a >= 0.f ? a : 0.01f * a;
        }
        half2_t* po = reinterpret_cast<half2_t*>(ob + mt * 16 + kq * 4);
        po[0] = half2_t{ (_Float16)av[0], (_Float16)av[1] };
        po[1] = half2_t{ (_Float16)av[2], (_Float16)av[3] };
    }
}

// ---- deformable conv 3x3x3: ci-split 3 (16 ch), packed fp16 interp + dot2 matmul ----
struct h8v { half2_t a, b, c, d; };   // 16 bytes = 8 halves

__global__ __launch_bounds__(256, 4)
void deform_kernel(const __half* __restrict__ a1h, const float* __restrict__ off,
                   const float* __restrict__ off_b,
                   const half2_t* __restrict__ wt, float* __restrict__ out) {
    int tid = threadIdx.x;
    int gc = blockIdx.y;
    int b = blockIdx.z;
    int s = blockIdx.x * 256 + tid;
    int z = s >> 10, y = (s >> 5) & 31, xx = s & 31;
    const __half* abase = a1h + (size_t)b * SVOL * CCH + gc * 16;
    const float* ob = off + (size_t)b * 81 * SVOL + s;
    float acc[CCH];
    #pragma unroll
    for (int o = 0; o < CCH; o++) acc[o] = 0.f;
    for (int k = 0; k < 27; k++) {
        int kd = k / 9 - 1, kh = (k / 3) % 3 - 1, kw = k % 3 - 1;
        float zf = (float)(z + kd) + ob[(size_t)(k * 3 + 0) * SVOL] + off_b[k * 3 + 0];
        float yf = (float)(y + kh) + ob[(size_t)(k * 3 + 1) * SVOL] + off_b[k * 3 + 1];
        float xf = (float)(xx + kw) + ob[(size_t)(k * 3 + 2) * SVOL] + off_b[k * 3 + 2];
        float z0 = floorf(zf), y0 = floorf(yf), x0 = floorf(xf);
        float tz = zf - z0, ty = yf - y0, tx = xf - x0;
        int iz0 = (int)z0, iy0 = (int)y0, ix0 = (int)x0;
        half2_t val2[8];
        #pragma unroll
        for (int j = 0; j < 8; j++) val2[j] = (half2_t)(_Float16)0;
        #pragma unroll
        for (int corner = 0; corner < 8; corner++) {
            int dz = corner >> 2, dy = (corner >> 1) & 1, dx = corner & 1;
            int zi = iz0 + dz, yi = iy0 + dy, xi = ix0 + dx;
            bool valid = (zi >= 0 && zi < 32 && yi >= 0 && yi < 32 && xi >= 0 && xi < 32);
            float wgt = (dz ? tz : 1.f - tz) * (dy ? ty : 1.f - ty) * (dx ? tx : 1.f - tx);
            float cwv = valid ? wgt : 0.f;
            _Float16 cwh = (_Float16)cwv;
            half2_t cw2 = { cwh, cwh };
            int zc = min(max(zi, 0), 31), yc = min(max(yi, 0), 31), xc = min(max(xi, 0), 31);
            int cidx = (zc * 32 + yc) * 32 + xc;
            const h8v* pv = (const h8v*)(abase + (size_t)cidx * CCH);
            h8v q0 = pv[0], q1 = pv[1];
            val2[0] += cw2 * q0.a;  val2[1] += cw2 * q0.b;
            val2[2] += cw2 * q0.c;  val2[3] += cw2 * q0.d;
            val2[4] += cw2 * q1.a;  val2[5] += cw2 * q1.b;
            val2[6] += cw2 * q1.c;  val2[7] += cw2 * q1.d;
        }
        #pragma unroll
        for (int cpl = 0; cpl < 8; cpl++) {
            half2_t v2 = val2[cpl];
            const half2_t* wr = wt + ((size_t)k * 24 + gc * 8 + cpl) * CCH;
            #pragma unroll
            for (int o = 0; o < CCH; o++) acc[o] = dot2f(v2, wr[o], acc[o]);
        }
    }
    float* op = out + (size_t)b * CCH * SVOL + s;
    #pragma unroll
    for (int o = 0; o < CCH; o++) atomicAdd(&op[(size_t)o * SVOL], acc[o]);
}

// ---- gate1: a2 = (c1 . dc + cb) * u; writes half2-pair a2p ----
__global__ __launch_bounds__(256, 4)
void gate1_kernel(const float* __restrict__ dc, const float* __restrict__ u,
                  const float* __restrict__ wt, const float* __restrict__ cb,
                  half2_t* __restrict__ a2p) {
    int tid = threadIdx.x;
    int g = blockIdx.y, b = blockIdx.z;
    int s = blockIdx.x * 256 + tid;
    size_t base = (size_t)b * CCH * SVOL + s;
    float acc[12];
    #pragma unroll
    for (int o = 0; o < 12; o++) acc[o] = cb[g * 12 + o];
    for (int ci = 0; ci < CCH; ci++) {
        float v = dc[base + (size_t)ci * SVOL];
        const float* wr = wt + ci * CCH + g * 12;
        #pragma unroll
        for (int o = 0; o < 12; o++) acc[o] += wr[o] * v;
    }
    #pragma unroll
    for (int o = 0; o < 12; o++) acc[o] *= u[base + (size_t)(g * 12 + o) * SVOL];
    half2_t* ap = a2p + ((size_t)b * 24 + g * 6) * SVOL + s;
    #pragma unroll
    for (int j = 0; j < 6; j++)
        ap[(size_t)j * SVOL] = half2_t{ (_Float16)acc[2 * j], (_Float16)acc[2 * j + 1] };
}

// ---- gate2: skip = x + gamma*(p2 . a2 + p2b + xn); writes fp32 skip + channel-last skh ----
__global__ __launch_bounds__(256, 4)
void gate2_kernel(const half2_t* __restrict__ a2p, const float* __restrict__ xn,
                  const float* __restrict__ x,
                  const half2_t* __restrict__ wt, const float* __restrict__ p2b,
                  const float* __restrict__ gamma, float* __restrict__ skip,
                  __half* __restrict__ skh) {
    int tid = threadIdx.x;
    int g = blockIdx.y, b = blockIdx.z;
    int s = blockIdx.x * 256 + tid;
    size_t base = (size_t)b * CCH * SVOL + s;
    const half2_t* ab = a2p + (size_t)b * 24 * SVOL + s;
    float acc[12];
    #pragma unroll
    for (int o = 0; o < 12; o++) acc[o] = p2b[g * 12 + o];
    for (int cp = 0; cp < 24; cp++) {
        half2_t v2 = ab[(size_t)cp * SVOL];
        const half2_t* wr = wt + cp * CCH + g * 12;
        #pragma unroll
        for (int o = 0; o < 12; o++) acc[o] = dot2f(v2, wr[o], acc[o]);
    }
    float sv[12];
    #pragma unroll
    for (int o = 0; o < 12; o++) {
        int oc = g * 12 + o;
        float vv = acc[o] + xn[base + (size_t)oc * SVOL];
        sv[o] = x[base + (size_t)oc * SVOL] + gamma[oc] * vv;
        skip[base + (size_t)oc * SVOL] = sv[o];
    }
    half2_t* sh = reinterpret_cast<half2_t*>(skh + ((size_t)b * SVOL + s) * CCH + g * 12);
    #pragma unroll
    for (int j = 0; j < 6; j++)
        sh[j] = half2_t{ (_Float16)sv[2 * j], (_Float16)sv[2 * j + 1] };
}

// ---- pr_final: out = skip + pr(attn), fp16 dot2; reads channel-last attnh ----
__global__ __launch_bounds__(256, 4)
void pr_final_kernel(const __half* __restrict__ attnh, const float* __restrict__ skip,
                     const half2_t* __restrict__ wt, const float* __restrict__ prb,
                     float* __restrict__ out) {
    int tid = threadIdx.x;
    int g = blockIdx.y, b = blockIdx.z;
    int s = blockIdx.x * 256 + tid;
    size_t base = (size_t)b * CCH * SVOL + s;
    const half2_t* ab = reinterpret_cast<const half2_t*>(attnh + ((size_t)b * SVOL + s) * CCH);
    float acc[12];
    #pragma unroll
    for (int o = 0; o < 12; o++) acc[o] = prb[g * 12 + o];
    for (int cp = 0; cp < 24; cp++) {
        half2_t v2 = ab[cp];
        const half2_t* wr = wt + cp * CCH + g * 12;
        #pragma unroll
        for (int o = 0; o < 12; o++) acc[o] = dot2f(v2, wr[o], acc[o]);
    }
    #pragma unroll
    for (int o = 0; o < 12; o++) {
        int oc = g * 12 + o;
        out[base + (size_t)oc * SVOL] = skip[base + (size_t)oc * SVOL] + acc[o];
    }
}

extern "C" void kernel_launch(void* const* d_in, const int* in_sizes, int n_in,
                              void* d_out, int out_size, void* d_ws, size_t ws_size,
                              hipStream_t stream) {
    (void)in_sizes; (void)n_in; (void)out_size; (void)ws_size;
    const float* x     = (const float*)d_in[0];
    const float* ln_s  = (const float*)d_in[1];
    const float* ln_b  = (const float*)d_in[2];
    const float* gamma = (const float*)d_in[3];
    const float* p1_w  = (const float*)d_in[4];
    const float* p1_b  = (const float*)d_in[5];
    const float* p2_w  = (const float*)d_in[6];
    const float* p2_b  = (const float*)d_in[7];
    const float* c0_w  = (const float*)d_in[8];
    const float* c0_b  = (const float*)d_in[9];
    const float* cs_w  = (const float*)d_in[10];
    const float* cs_b  = (const float*)d_in[11];
    const float* off_w = (const float*)d_in[12];
    const float* off_b = (const float*)d_in[13];
    const float* dc_w  = (const float*)d_in[14];
    const float* dc_b  = (const float*)d_in[15];
    const float* c1_w  = (const float*)d_in[16];
    const float* c1_b  = (const float*)d_in[17];
    const float* u1_w  = (const float*)d_in[18];
    const float* bn1_s = (const float*)d_in[19];
    const float* bn1_b = (const float*)d_in[20];
    const float* bn1_m = (const float*)d_in[21];
    const float* bn1_v = (const float*)d_in[22];
    const float* u2_w  = (const float*)d_in[23];
    const float* bn2_s = (const float*)d_in[24];
    const float* bn2_b = (const float*)d_in[25];
    const float* bn2_m = (const float*)d_in[26];
    const float* bn2_v = (const float*)d_in[27];
    const float* pr_w  = (const float*)d_in[28];
    const float* pr_b  = (const float*)d_in[29];
    float* out = (float*)d_out;

    float* wsf = (float*)d_ws;
    const size_t TS = (size_t)NB * CCH * SVOL;   // 3,145,728 floats
    float* xn   = out;            // d_out doubles as xn fp32 (dead after gate2)
    float* ubuf = wsf;            // u (gelu out fp32) -> [skh | h1h] (fp16 ch-last)
    float* bufA = wsf + TS;       // dw5 out -> a1h -> skip (fp32)
    float* bufB = wsf + 2 * TS;   // xnp (half2) -> dw7 out (a1) -> deform partials (dc)
    float* offb = wsf + 3 * TS;   // offsets [B,81,S] -> a2p (half2) -> attnh (fp16 ch-last)
    float* wtb    = wsf + 3 * TS + (size_t)NB * 81 * SVOL;
    float* wt_offf = wtb;                   // off MFMA A-frags: 31104 half4
    float* wt_dcf  = wt_offf + 104976;      // dc pair weights
    float* wt_u1f  = wt_dcf + 62208;        // u1 MFMA A-frags: 15552 half4
    float* wt_u2f  = wt_u1f + 62208;        // u2 MFMA A-frags
    float* pt_p1  = wt_u2f + 62208;
    float* pt_c1  = pt_p1 + 2304;
    float* pt_p2  = pt_c1 + 2304;
    float* pt_pr  = pt_p2 + 2304;
    float* cb_all = pt_pr + 2304;

    __half*  a1h = (__half*)bufA;
    __half*  skh = (__half*)ubuf;                   // gate2 out (u dead)
    __half*  h1h = (__half*)(ubuf + TS / 2);        // u1 out
    half2_t* xnp = (half2_t*)bufB;
    half2_t* a2p = (half2_t*)offb;
    __half*  attnh = (__half*)offb;                 // a2p dead after gate2
    half4_t* wA_off = (half4_t*)wt_offf;
    half2_t* wt_dch  = (half2_t*)wt_dcf;
    half4_t* wA_u1 = (half4_t*)wt_u1f;
    half4_t* wA_u2 = (half4_t*)wt_u2f;
    half2_t* wt_p1h  = (half2_t*)pt_p1;
    half2_t* wt_p2h  = (half2_t*)pt_p2;
    half2_t* wt_prh  = (half2_t*)pt_pr;

    dim3 blk(256);
    dim3 gpos(SVOL / 256, NB);
    dim3 g4(SVOL / 256, 4, NB);
    dim3 gmf(512, NB);                 // MFMA conv kernels: 8x8x8 spatial tiles
    dim3 g3d(SVOL / 256, 3, NB);
    dim3 gdwc(8, CCH, NB);
    dim3 gtr(SVOL / 64, NB);

    hipLaunchKernelGGL(reshape_mfma_off_kernel, dim3((31104 + 255) / 256), blk, 0, stream, off_w, wA_off);
    hipLaunchKernelGGL(reshape_mfma48_kernel, dim3((15552 + 255) / 256), blk, 0, stream, u1_w, wA_u1);
    hipLaunchKernelGGL(reshape_mfma48_kernel, dim3((15552 + 255) / 256), blk, 0, stream, u2_w, wA_u2);
    hipLaunchKernelGGL(reshape_pair_kernel, dim3((27 * 24 * 48 + 255) / 256), blk, 0, stream, dc_w, wt_dch, 48);
    hipLaunchKernelGGL(t1x1_pair_kernel, dim3(5), blk, 0, stream, p1_w, wt_p1h);
    hipLaunchKernelGGL(t1x1_pair_kernel, dim3(5), blk, 0, stream, p2_w, wt_p2h);
    hipLaunchKernelGGL(t1x1_pair_kernel, dim3(5), blk, 0, stream, pr_w, wt_prh);
    hipLaunchKernelGGL(t1x1_kernel, dim3(9), blk, 0, stream, c1_w, pt_c1);
    hipLaunchKernelGGL(cb_kernel, dim3(1), dim3(64), 0, stream, c1_w, c1_b, dc_b, cb_all);

    hipLaunchKernelGGL(ln_kernel,            gpos, blk, 0, stream, x, ln_s, ln_b, xn, xnp);
    hipLaunchKernelGGL(p1_gelu_kernel,       g4,   blk, 0, stream, xnp, wt_p1h, p1_b, ubuf);
    hipLaunchKernelGGL(dw5_kernel,           gdwc, blk, 0, stream, ubuf, c0_w, c0_b, bufA);
    hipLaunchKernelGGL(dw7_kernel,           gdwc, blk, 0, stream, bufA, cs_w, cs_b, bufB);
    hipLaunchKernelGGL(transpose_pack_kernel, gtr, blk, 0, stream, bufB, a1h);
    hipLaunchKernelGGL(offconv_mfma_kernel,  gmf,  blk, 0, stream, a1h, wA_off, offb);
    hipMemsetAsync(bufB, 0, TS * sizeof(float), stream);
    hipLaunchKernelGGL(deform_kernel,        g3d,  blk, 0, stream, a1h, offb, off_b, wt_dch, bufB);
    hipLaunchKernelGGL(gate1_kernel,         g4,   blk, 0, stream, bufB, ubuf, pt_c1, cb_all, a2p);
    hipLaunchKernelGGL(gate2_kernel,         g4,   blk, 0, stream, a2p, xn, x, wt_p2h, p2_b, gamma,
                       bufA, skh);
    hipLaunchKernelGGL(u1_mfma_kernel,       gmf,  blk, 0, stream, skh, wA_u1,
                       bn1_s, bn1_b, bn1_m, bn1_v, h1h);
    hipLaunchKernelGGL(u2_mfma_kernel,       gmf,  blk, 0, stream, h1h, bufA, wA_u2,
                       bn2_s, bn2_b, bn2_m, bn2_v, attnh);
    hipLaunchKernelGGL(pr_final_kernel,      g4,   blk, 0, stream, attnh, bufA, wt_prh, pr_b, out);
}

// Round 26
// 483.266 us; speedup vs baseline: 1.2685x; 1.0440x over previous
//
#include <hip/hip_runtime.h>
#include <hip/hip_fp16.h>
#include <math.h>

#define CCH 48
#define SDIM 32
#define SVOL (SDIM*SDIM*SDIM)
#define NB 2

typedef _Float16 half2_t __attribute__((ext_vector_type(2)));
typedef _Float16 half4_t __attribute__((ext_vector_type(4)));
typedef float float4_t __attribute__((ext_vector_type(4)));

static __device__ __forceinline__ float dot2f(half2_t a, half2_t b, float c) {
#if __has_builtin(__builtin_amdgcn_fdot2)
    return __builtin_amdgcn_fdot2(a, b, c, false);
#else
    return c + (float)a[0] * (float)b[0] + (float)a[1] * (float)b[1];
#endif
}

// ======== one-off weight reshape kernels ========

// off_w[81][48][27] -> MFMA A-fragments: e = (((tap*6+mt)*3+ks)*4+kq)*16+row, rows 81..95 zero.
__global__ __launch_bounds__(256)
void reshape_mfma_off_kernel(const float* __restrict__ w, half4_t* __restrict__ wA) {
    int e = blockIdx.x * 256 + threadIdx.x;
    if (e < 31104) {
        int row = e & 15;
        int kq = (e >> 4) & 3;
        int ks = (e / 64) % 3;
        int mt = (e / 192) % 6;
        int tap = e / 1152;
        int o = mt * 16 + row;
        half4_t v;
        #pragma unroll
        for (int h = 0; h < 4; h++) {
            int ci = ks * 16 + kq * 4 + h;
            float val = (o < 81) ? w[((size_t)o * CCH + ci) * 27 + tap] : 0.f;
            v[h] = (_Float16)val;
        }
        wA[e] = v;
    }
}

// w[48][48][27] -> MFMA A-fragments (M=48, 3 mt): e = (((tap*3+mt)*3+ks)*4+kq)*16+row
__global__ __launch_bounds__(256)
void reshape_mfma48_kernel(const float* __restrict__ w, half4_t* __restrict__ wA) {
    int e = blockIdx.x * 256 + threadIdx.x;
    if (e < 15552) {
        int row = e & 15;
        int kq = (e >> 4) & 3;
        int ks = (e / 64) % 3;
        int mt = (e / 192) % 3;
        int tap = e / 576;
        int o = mt * 16 + row;
        half4_t v;
        #pragma unroll
        for (int h = 0; h < 4; h++) {
            int ci = ks * 16 + kq * 4 + h;
            v[h] = (_Float16)w[((size_t)o * CCH + ci) * 27 + tap];
        }
        wA[e] = v;
    }
}

// dc_w[48][48][27] -> per-gc MFMA A-fragments (K=16): e = ((((gc*27+tap)*3+mt)*4)+kq)*16+row
__global__ __launch_bounds__(256)
void reshape_mfma_dc_kernel(const float* __restrict__ w, half4_t* __restrict__ wA) {
    int e = blockIdx.x * 256 + threadIdx.x;
    if (e < 15552) {
        int row = e & 15;
        int kq = (e >> 4) & 3;
        int mt = (e / 64) % 3;
        int tap = (e / 192) % 27;
        int gc = e / 5184;
        int o = mt * 16 + row;
        half4_t v;
        #pragma unroll
        for (int h = 0; h < 4; h++) {
            int ci = gc * 16 + kq * 4 + h;
            v[h] = (_Float16)w[((size_t)o * CCH + ci) * 27 + tap];
        }
        wA[e] = v;
    }
}

__global__ __launch_bounds__(256)
void t1x1_pair_kernel(const float* __restrict__ w, half2_t* __restrict__ wt) {
    int i = blockIdx.x * 256 + threadIdx.x;
    if (i < 24 * CCH) {
        int o = i % CCH, cp = i / CCH;
        wt[i] = half2_t{ (_Float16)w[o * CCH + 2 * cp], (_Float16)w[o * CCH + 2 * cp + 1] };
    }
}

__global__ __launch_bounds__(256)
void t1x1_kernel(const float* __restrict__ w, float* __restrict__ wt) {
    int i = blockIdx.x * 256 + threadIdx.x;
    if (i < CCH * CCH) { int ci = i / CCH, o = i % CCH; wt[i] = w[o * CCH + ci]; }
}

__global__ __launch_bounds__(64)
void cb_kernel(const float* __restrict__ c1w, const float* __restrict__ c1b,
               const float* __restrict__ dcb, float* __restrict__ cb) {
    int o = threadIdx.x;
    if (o < CCH) {
        float v = c1b[o];
        for (int ci = 0; ci < CCH; ci++) v += c1w[o * CCH + ci] * dcb[ci];
        cb[o] = v;
    }
}

// ---------------- LayerNorm over C; writes fp32 xn AND half2-pair xnp ----------------
__global__ __launch_bounds__(256)
void ln_kernel(const float* __restrict__ x, const float* __restrict__ ln_s,
               const float* __restrict__ ln_b, float* __restrict__ xn,
               half2_t* __restrict__ xnp) {
    int s = blockIdx.x * 256 + threadIdx.x;
    int b = blockIdx.y;
    const float* xb = x + (size_t)b * CCH * SVOL + s;
    float v[CCH];
    float mu = 0.f;
    #pragma unroll
    for (int c = 0; c < CCH; c++) { v[c] = xb[c * SVOL]; mu += v[c]; }
    mu *= (1.0f / CCH);
    float var = 0.f;
    #pragma unroll
    for (int c = 0; c < CCH; c++) { float d = v[c] - mu; var += d * d; }
    var *= (1.0f / CCH);
    float inv = rsqrtf(var + 1e-5f);
    float* o = xn + (size_t)b * CCH * SVOL + s;
    float nv[CCH];
    #pragma unroll
    for (int c = 0; c < CCH; c++) { nv[c] = (v[c] - mu) * inv * ln_s[c] + ln_b[c]; o[c * SVOL] = nv[c]; }
    half2_t* xp = xnp + (size_t)b * 24 * SVOL + s;
    #pragma unroll
    for (int cp = 0; cp < 24; cp++)
        xp[(size_t)cp * SVOL] = half2_t{ (_Float16)nv[2 * cp], (_Float16)nv[2 * cp + 1] };
}

// ---------------- 1x1x1 conv + exact GELU (4 groups x 12), fp16 dot2 ----------------
__global__ __launch_bounds__(256, 4)
void p1_gelu_kernel(const half2_t* __restrict__ xnp, const half2_t* __restrict__ wt,
                    const float* __restrict__ bias, float* __restrict__ u) {
    int tid = threadIdx.x;
    int g = blockIdx.y, b = blockIdx.z;
    int s = blockIdx.x * 256 + tid;
    const half2_t* xb = xnp + (size_t)b * 24 * SVOL + s;
    float acc[12];
    #pragma unroll
    for (int o = 0; o < 12; o++) acc[o] = bias[g * 12 + o];
    for (int cp = 0; cp < 24; cp++) {
        half2_t v2 = xb[(size_t)cp * SVOL];
        const half2_t* wr = wt + cp * CCH + g * 12;
        #pragma unroll
        for (int o = 0; o < 12; o++) acc[o] = dot2f(v2, wr[o], acc[o]);
    }
    float* ub = u + (size_t)b * CCH * SVOL + s + (size_t)(g * 12) * SVOL;
    #pragma unroll
    for (int o = 0; o < 12; o++) {
        float a = acc[o];
        ub[o * SVOL] = 0.5f * a * (1.0f + erff(a * 0.70710678118654752f));
    }
}

// ---- depthwise 5x5x5 pad 2: half-column blocking (16 z/thread, window cache) ----
__global__ __launch_bounds__(256, 4)
void dw5_kernel(const float* __restrict__ in, const float* __restrict__ w,
                const float* __restrict__ bias, float* __restrict__ out) {
    int tid = threadIdx.x;
    int c = blockIdx.y, b = blockIdx.z;
    const float* wc = w + c * 125;
    int bx = blockIdx.x;
    int yx = (bx >> 1) * 256 + tid;
    int z0 = (bx & 1) * 16;
    int y = yx >> 5, xx = yx & 31;
    const float* ib = in + ((size_t)b * CCH + c) * SVOL;
    float acc[16];
    float bv = bias[c];
    #pragma unroll
    for (int z = 0; z < 16; z++) acc[z] = bv;
    for (int ty = 0; ty < 5; ty++) {
        int yy = y + ty - 2; if (yy < 0 || yy >= 32) continue;
        for (int tx = 0; tx < 5; tx++) {
            int xv = xx + tx - 2; if (xv < 0 || xv >= 32) continue;
            const float* col = ib + yy * 32 + xv;
            float cv[20];
            #pragma unroll
            for (int j = 0; j < 20; j++) {
                int zz = z0 - 2 + j;
                cv[j] = (zz >= 0 && zz < 32) ? col[(size_t)zz * 1024] : 0.f;
            }
            #pragma unroll
            for (int tz = 0; tz < 5; tz++) {
                float wv = wc[(tz * 5 + ty) * 5 + tx];
                #pragma unroll
                for (int z = 0; z < 16; z++) acc[z] += wv * cv[z + tz];
            }
        }
    }
    float* ob = out + ((size_t)b * CCH + c) * SVOL + y * 32 + xx;
    #pragma unroll
    for (int z = 0; z < 16; z++) ob[(size_t)(z0 + z) * 1024] = acc[z];
}

// ---- depthwise 7x7x7 dil 3 pad 9: half-column blocking (16 z/thread, window cache) ----
__global__ __launch_bounds__(256, 4)
void dw7_kernel(const float* __restrict__ in, const float* __restrict__ w,
                const float* __restrict__ bias, float* __restrict__ out) {
    int tid = threadIdx.x;
    int c = blockIdx.y, b = blockIdx.z;
    const float* wc = w + c * 343;
    int bx = blockIdx.x;
    int yx = (bx >> 1) * 256 + tid;
    int z0 = (bx & 1) * 16;
    int y = yx >> 5, xx = yx & 31;
    const float* ib = in + ((size_t)b * CCH + c) * SVOL;
    float acc[16];
    float bv = bias[c];
    #pragma unroll
    for (int z = 0; z < 16; z++) acc[z] = bv;
    for (int ty = 0; ty < 7; ty++) {
        int yy = y + 3 * (ty - 3); if (yy < 0 || yy >= 32) continue;
        for (int tx = 0; tx < 7; tx++) {
            int xv = xx + 3 * (tx - 3); if (xv < 0 || xv >= 32) continue;
            const float* col = ib + yy * 32 + xv;
            float cv[34];
            #pragma unroll
            for (int j = 0; j < 34; j++) {
                int zz = z0 - 9 + j;
                cv[j] = (zz >= 0 && zz < 32) ? col[(size_t)zz * 1024] : 0.f;
            }
            #pragma unroll
            for (int tz = 0; tz < 7; tz++) {
                float wv = wc[(tz * 7 + ty) * 7 + tx];
                #pragma unroll
                for (int z = 0; z < 16; z++) acc[z] += wv * cv[z + 3 * tz];
            }
        }
    }
    float* ob = out + ((size_t)b * CCH + c) * SVOL + y * 32 + xx;
    #pragma unroll
    for (int z = 0; z < 16; z++) ob[(size_t)(z0 + z) * 1024] = acc[z];
}

// ---- a1 fp32 [48][S] -> a1h fp16 [S][48] ----
__global__ __launch_bounds__(256)
void transpose_pack_kernel(const float* __restrict__ a1, __half* __restrict__ a1h) {
    __shared__ float tile[CCH * 65];
    int tid = threadIdx.x;
    int b = blockIdx.y;
    int s0 = blockIdx.x * 64;
    const float* ib = a1 + (size_t)b * CCH * SVOL + s0;
    for (int i = tid; i < CCH * 64; i += 256) {
        int c = i >> 6, p = i & 63;
        tile[c * 65 + p] = ib[(size_t)c * SVOL + p];
    }
    __syncthreads();
    __half* ob = a1h + ((size_t)b * SVOL + s0) * CCH;
    for (int i = tid; i < 64 * CCH; i += 256) {
        int p = i / CCH, c = i % CCH;
        ob[i] = __float2half(tile[c * 65 + p]);
    }
}

// ---- offset conv 3x3x3 via MFMA implicit-GEMM: 4x4x4 tile, halo in LDS, no atomics ----
__global__ __launch_bounds__(256, 4)
void offconv_mfma_kernel(const __half* __restrict__ a1h, const half4_t* __restrict__ wA,
                         float* __restrict__ off) {
    __shared__ __half halo[216 * 52];
    int tid = threadIdx.x;
    int t = blockIdx.x;
    int b = blockIdx.y;
    int tz0 = (t >> 6) * 4, ty0 = ((t >> 3) & 7) * 4, tx0 = (t & 7) * 4;
    const __half* ab = a1h + (size_t)b * SVOL * CCH;
    for (int idx = tid; idx < 216 * 24; idx += 256) {
        int hpos = idx / 24, kp = idx % 24;
        int hz = hpos / 36, hy = (hpos / 6) % 6, hx = hpos % 6;
        int gz = tz0 + hz - 1, gy = ty0 + hy - 1, gx = tx0 + hx - 1;
        unsigned int v = 0u;
        if (gz >= 0 && gz < 32 && gy >= 0 && gy < 32 && gx >= 0 && gx < 32) {
            int s = (gz * 32 + gy) * 32 + gx;
            v = *reinterpret_cast<const unsigned int*>(ab + (size_t)s * CCH + kp * 2);
        }
        *reinterpret_cast<unsigned int*>(&halo[hpos * 52 + kp * 2]) = v;
    }
    __syncthreads();
    int wave = tid >> 6, lane = tid & 63;
    int col = lane & 15;
    int kq = lane >> 4;
    int py = col >> 2, px = col & 3;
    int pz = wave;
    float4_t acc[6];
    #pragma unroll
    for (int m = 0; m < 6; m++) acc[m] = (float4_t)0.f;
    for (int tap = 0; tap < 27; tap++) {
        int dz = tap / 9, dy = (tap / 3) % 3, dx = tap % 3;
        int hbase = ((pz + dz) * 36 + (py + dy) * 6 + (px + dx)) * 52 + kq * 4;
        half4_t bf0 = *reinterpret_cast<const half4_t*>(&halo[hbase]);
        half4_t bf1 = *reinterpret_cast<const half4_t*>(&halo[hbase + 16]);
        half4_t bf2 = *reinterpret_cast<const half4_t*>(&halo[hbase + 32]);
        #pragma unroll
        for (int mt = 0; mt < 6; mt++) {
            int fb = (tap * 6 + mt) * 12 + kq;
            half4_t a0 = wA[(size_t)fb * 16 + col];
            half4_t a1 = wA[(size_t)(fb + 4) * 16 + col];
            half4_t a2 = wA[(size_t)(fb + 8) * 16 + col];
            acc[mt] = __builtin_amdgcn_mfma_f32_16x16x16f16(a0, bf0, acc[mt], 0, 0, 0);
            acc[mt] = __builtin_amdgcn_mfma_f32_16x16x16f16(a1, bf1, acc[mt], 0, 0, 0);
            acc[mt] = __builtin_amdgcn_mfma_f32_16x16x16f16(a2, bf2, acc[mt], 0, 0, 0);
        }
    }
    int sg = ((tz0 + pz) * 32 + ty0 + py) * 32 + tx0 + px;
    float* ob = off + (size_t)b * 81 * SVOL + sg;
    #pragma unroll
    for (int mt = 0; mt < 6; mt++) {
        #pragma unroll
        for (int r = 0; r < 4; r++) {
            int orow = mt * 16 + kq * 4 + r;
            if (orow < 81) ob[(size_t)orow * SVOL] = acc[mt][r];
        }
    }
}

// ---- u1 3x3x3 via MFMA + BN1 + LeakyReLU; in: skh [S][48] fp16, out: h1h [S][48] fp16 ----
__global__ __launch_bounds__(256, 4)
void u1_mfma_kernel(const __half* __restrict__ skh, const half4_t* __restrict__ wA,
                    const float* __restrict__ bs, const float* __restrict__ bb,
                    const float* __restrict__ bm, const float* __restrict__ bv,
                    __half* __restrict__ h1h) {
    __shared__ __half halo[216 * 52];
    int tid = threadIdx.x;
    int t = blockIdx.x;
    int b = blockIdx.y;
    int tz0 = (t >> 6) * 4, ty0 = ((t >> 3) & 7) * 4, tx0 = (t & 7) * 4;
    const __half* ab = skh + (size_t)b * SVOL * CCH;
    for (int idx = tid; idx < 216 * 24; idx += 256) {
        int hpos = idx / 24, kp = idx % 24;
        int hz = hpos / 36, hy = (hpos / 6) % 6, hx = hpos % 6;
        int gz = tz0 + hz - 1, gy = ty0 + hy - 1, gx = tx0 + hx - 1;
        unsigned int v = 0u;
        if (gz >= 0 && gz < 32 && gy >= 0 && gy < 32 && gx >= 0 && gx < 32) {
            int s = (gz * 32 + gy) * 32 + gx;
            v = *reinterpret_cast<const unsigned int*>(ab + (size_t)s * CCH + kp * 2);
        }
        *reinterpret_cast<unsigned int*>(&halo[hpos * 52 + kp * 2]) = v;
    }
    __syncthreads();
    int wave = tid >> 6, lane = tid & 63;
    int col = lane & 15;
    int kq = lane >> 4;
    int py = col >> 2, px = col & 3;
    int pz = wave;
    float4_t acc[3];
    #pragma unroll
    for (int m = 0; m < 3; m++) acc[m] = (float4_t)0.f;
    for (int tap = 0; tap < 27; tap++) {
        int dz = tap / 9, dy = (tap / 3) % 3, dx = tap % 3;
        int hbase = ((pz + dz) * 36 + (py + dy) * 6 + (px + dx)) * 52 + kq * 4;
        half4_t bf0 = *reinterpret_cast<const half4_t*>(&halo[hbase]);
        half4_t bf1 = *reinterpret_cast<const half4_t*>(&halo[hbase + 16]);
        half4_t bf2 = *reinterpret_cast<const half4_t*>(&halo[hbase + 32]);
        #pragma unroll
        for (int mt = 0; mt < 3; mt++) {
            int fb = (tap * 3 + mt) * 12 + kq;
            half4_t a0 = wA[(size_t)fb * 16 + col];
            half4_t a1 = wA[(size_t)(fb + 4) * 16 + col];
            half4_t a2 = wA[(size_t)(fb + 8) * 16 + col];
            acc[mt] = __builtin_amdgcn_mfma_f32_16x16x16f16(a0, bf0, acc[mt], 0, 0, 0);
            acc[mt] = __builtin_amdgcn_mfma_f32_16x16x16f16(a1, bf1, acc[mt], 0, 0, 0);
            acc[mt] = __builtin_amdgcn_mfma_f32_16x16x16f16(a2, bf2, acc[mt], 0, 0, 0);
        }
    }
    int sg = ((tz0 + pz) * 32 + ty0 + py) * 32 + tx0 + px;
    __half* ob = h1h + ((size_t)b * SVOL + sg) * CCH;
    #pragma unroll
    for (int mt = 0; mt < 3; mt++) {
        float hv[4];
        #pragma unroll
        for (int r = 0; r < 4; r++) {
            int orow = mt * 16 + kq * 4 + r;
            float inv = rsqrtf(bv[orow] + 1e-5f);
            float h = (acc[mt][r] - bm[orow]) * (bs[orow] * inv) + bb[orow];
            hv[r] = h >= 0.f ? h : 0.01f * h;
        }
        half2_t* po = reinterpret_cast<half2_t*>(ob + mt * 16 + kq * 4);
        po[0] = half2_t{ (_Float16)hv[0], (_Float16)hv[1] };
        po[1] = half2_t{ (_Float16)hv[2], (_Float16)hv[3] };
    }
}

// ---- u2 3x3x3 via MFMA + BN2 + (+skip fp32) + LeakyReLU; out: attnh [S][48] fp16 ----
__global__ __launch_bounds__(256, 4)
void u2_mfma_kernel(const __half* __restrict__ h1h, const float* __restrict__ skip,
                    const half4_t* __restrict__ wA,
                    const float* __restrict__ bs, const float* __restrict__ bb,
                    const float* __restrict__ bm, const float* __restrict__ bv,
                    __half* __restrict__ attnh) {
    __shared__ __half halo[216 * 52];
    int tid = threadIdx.x;
    int t = blockIdx.x;
    int b = blockIdx.y;
    int tz0 = (t >> 6) * 4, ty0 = ((t >> 3) & 7) * 4, tx0 = (t & 7) * 4;
    const __half* ab = h1h + (size_t)b * SVOL * CCH;
    for (int idx = tid; idx < 216 * 24; idx += 256) {
        int hpos = idx / 24, kp = idx % 24;
        int hz = hpos / 36, hy = (hpos / 6) % 6, hx = hpos % 6;
        int gz = tz0 + hz - 1, gy = ty0 + hy - 1, gx = tx0 + hx - 1;
        unsigned int v = 0u;
        if (gz >= 0 && gz < 32 && gy >= 0 && gy < 32 && gx >= 0 && gx < 32) {
            int s = (gz * 32 + gy) * 32 + gx;
            v = *reinterpret_cast<const unsigned int*>(ab + (size_t)s * CCH + kp * 2);
        }
        *reinterpret_cast<unsigned int*>(&halo[hpos * 52 + kp * 2]) = v;
    }
    __syncthreads();
    int wave = tid >> 6, lane = tid & 63;
    int col = lane & 15;
    int kq = lane >> 4;
    int py = col >> 2, px = col & 3;
    int pz = wave;
    float4_t acc[3];
    #pragma unroll
    for (int m = 0; m < 3; m++) acc[m] = (float4_t)0.f;
    for (int tap = 0; tap < 27; tap++) {
        int dz = tap / 9, dy = (tap / 3) % 3, dx = tap % 3;
        int hbase = ((pz + dz) * 36 + (py + dy) * 6 + (px + dx)) * 52 + kq * 4;
        half4_t bf0 = *reinterpret_cast<const half4_t*>(&halo[hbase]);
        half4_t bf1 = *reinterpret_cast<const half4_t*>(&halo[hbase + 16]);
        half4_t bf2 = *reinterpret_cast<const half4_t*>(&halo[hbase + 32]);
        #pragma unroll
        for (int mt = 0; mt < 3; mt++) {
            int fb = (tap * 3 + mt) * 12 + kq;
            half4_t a0 = wA[(size_t)fb * 16 + col];
            half4_t a1 = wA[(size_t)(fb + 4) * 16 + col];
            half4_t a2 = wA[(size_t)(fb + 8) * 16 + col];
            acc[mt] = __builtin_amdgcn_mfma_f32_16x16x16f16(a0, bf0, acc[mt], 0, 0, 0);
            acc[mt] = __builtin_amdgcn_mfma_f32_16x16x16f16(a1, bf1, acc[mt], 0, 0, 0);
            acc[mt] = __builtin_amdgcn_mfma_f32_16x16x16f16(a2, bf2, acc[mt], 0, 0, 0);
        }
    }
    int sg = ((tz0 + pz) * 32 + ty0 + py) * 32 + tx0 + px;
    const float* sk = skip + (size_t)b * CCH * SVOL + sg;
    __half* ob = attnh + ((size_t)b * SVOL + sg) * CCH;
    #pragma unroll
    for (int mt = 0; mt < 3; mt++) {
        float av[4];
        #pragma unroll
        for (int r = 0; r < 4; r++) {
            int orow = mt * 16 + kq * 4 + r;
            float inv = rsqrtf(bv[orow] + 1e-5f);
            float h = (acc[mt][r] - bm[orow]) * (bs[orow] * inv) + bb[orow];
            float a = h + sk[(size_t)orow * SVOL];
            av[r] = a >= 0.f ? a : 0.01f * a;
        }
        half2_t* po = reinterpret_cast<half2_t*>(ob + mt * 16 + kq * 4);
        po[0] = half2_t{ (_Float16)av[0], (_Float16)av[1] };
        po[1] = half2_t{ (_Float16)av[2], (_Float16)av[3] };
    }
}

// ---- deformable conv 3x3x3: ci-split 3, fp16 interp + MFMA matmul via wave-private LDS ----
struct h8v { half2_t a, b, c, d; };   // 16 bytes = 8 halves

__global__ __launch_bounds__(256, 4)
void deform_mfma_kernel(const __half* __restrict__ a1h, const float* __restrict__ off,
                        const float* __restrict__ off_b,
                        const half4_t* __restrict__ wA, float* __restrict__ out) {
    __shared__ __half vbuf[2][4][64][20];   // [parity][wave][pos][16ch + 4 pad] = 20 KB
    int tid = threadIdx.x;
    int gc = blockIdx.y;            // ci group 0..2 (16 ch)
    int b = blockIdx.z;
    int wave = tid >> 6, lane = tid & 63;
    int col = lane & 15, kq = lane >> 4;
    int s = blockIdx.x * 256 + tid;
    int z = s >> 10, y = (s >> 5) & 31, xx = s & 31;
    const __half* abase = a1h + (size_t)b * SVOL * CCH + gc * 16;
    const float* ob = off + (size_t)b * 81 * SVOL + s;
    float4_t acc[3][4];
    #pragma unroll
    for (int m = 0; m < 3; m++)
        #pragma unroll
        for (int c = 0; c < 4; c++) acc[m][c] = (float4_t)0.f;
    for (int k = 0; k < 27; k++) {
        int kd = k / 9 - 1, kh = (k / 3) % 3 - 1, kw = k % 3 - 1;
        float zf = (float)(z + kd) + ob[(size_t)(k * 3 + 0) * SVOL] + off_b[k * 3 + 0];
        float yf = (float)(y + kh) + ob[(size_t)(k * 3 + 1) * SVOL] + off_b[k * 3 + 1];
        float xf = (float)(xx + kw) + ob[(size_t)(k * 3 + 2) * SVOL] + off_b[k * 3 + 2];
        float z0 = floorf(zf), y0 = floorf(yf), x0 = floorf(xf);
        float tz = zf - z0, ty = yf - y0, tx = xf - x0;
        int iz0 = (int)z0, iy0 = (int)y0, ix0 = (int)x0;
        half2_t val2[8];
        #pragma unroll
        for (int j = 0; j < 8; j++) val2[j] = (half2_t)(_Float16)0;
        #pragma unroll
        for (int corner = 0; corner < 8; corner++) {
            int dz = corner >> 2, dy = (corner >> 1) & 1, dx = corner & 1;
            int zi = iz0 + dz, yi = iy0 + dy, xi = ix0 + dx;
            bool valid = (zi >= 0 && zi < 32 && yi >= 0 && yi < 32 && xi >= 0 && xi < 32);
            float wgt = (dz ? tz : 1.f - tz) * (dy ? ty : 1.f - ty) * (dx ? tx : 1.f - tx);
            float cwv = valid ? wgt : 0.f;
            _Float16 cwh = (_Float16)cwv;
            half2_t cw2 = { cwh, cwh };
            int zc = min(max(zi, 0), 31), yc = min(max(yi, 0), 31), xc = min(max(xi, 0), 31);
            int cidx = (zc * 32 + yc) * 32 + xc;
            const h8v* pv = (const h8v*)(abase + (size_t)cidx * CCH);
            h8v q0 = pv[0], q1 = pv[1];
            val2[0] += cw2 * q0.a;  val2[1] += cw2 * q0.b;
            val2[2] += cw2 * q0.c;  val2[3] += cw2 * q0.d;
            val2[4] += cw2 * q1.a;  val2[5] += cw2 * q1.b;
            val2[6] += cw2 * q1.c;  val2[7] += cw2 * q1.d;
        }
        // stage 16 interpolated channels into wave-private LDS (parity double-buffer)
        __half* vb = &vbuf[k & 1][wave][lane][0];
        half4_t* vb4 = reinterpret_cast<half4_t*>(vb);
        vb4[0] = half4_t{ val2[0][0], val2[0][1], val2[1][0], val2[1][1] };
        vb4[1] = half4_t{ val2[2][0], val2[2][1], val2[3][0], val2[3][1] };
        vb4[2] = half4_t{ val2[4][0], val2[4][1], val2[5][0], val2[5][1] };
        vb4[3] = half4_t{ val2[6][0], val2[6][1], val2[7][0], val2[7][1] };
        // A fragments for this tap (reused across 4 col-tiles)
        half4_t a0, a1, a2;
        {
            int fb = ((gc * 27 + k) * 3 + 0) * 4 + kq;
            a0 = wA[(size_t)fb * 16 + col];
            a1 = wA[(size_t)(fb + 4) * 16 + col];
            a2 = wA[(size_t)(fb + 8) * 16 + col];
        }
        #pragma unroll
        for (int ct = 0; ct < 4; ct++) {
            half4_t bf = *reinterpret_cast<const half4_t*>(&vbuf[k & 1][wave][ct * 16 + col][kq * 4]);
            acc[0][ct] = __builtin_amdgcn_mfma_f32_16x16x16f16(a0, bf, acc[0][ct], 0, 0, 0);
            acc[1][ct] = __builtin_amdgcn_mfma_f32_16x16x16f16(a1, bf, acc[1][ct], 0, 0, 0);
            acc[2][ct] = __builtin_amdgcn_mfma_f32_16x16x16f16(a2, bf, acc[2][ct], 0, 0, 0);
        }
    }
    int sbase = blockIdx.x * 256 + wave * 64;
    float* op = out + (size_t)b * CCH * SVOL;
    #pragma unroll
    for (int mt = 0; mt < 3; mt++) {
        #pragma unroll
        for (int ct = 0; ct < 4; ct++) {
            int sp = sbase + ct * 16 + col;
            #pragma unroll
            for (int r = 0; r < 4; r++) {
                int o = mt * 16 + kq * 4 + r;
                atomicAdd(&op[(size_t)o * SVOL + sp], acc[mt][ct][r]);
            }
        }
    }
}

// ---- gate1: a2 = (c1 . dc + cb) * u; writes half2-pair a2p ----
__global__ __launch_bounds__(256, 4)
void gate1_kernel(const float* __restrict__ dc, const float* __restrict__ u,
                  const float* __restrict__ wt, const float* __restrict__ cb,
                  half2_t* __restrict__ a2p) {
    int tid = threadIdx.x;
    int g = blockIdx.y, b = blockIdx.z;
    int s = blockIdx.x * 256 + tid;
    size_t base = (size_t)b * CCH * SVOL + s;
    float acc[12];
    #pragma unroll
    for (int o = 0; o < 12; o++) acc[o] = cb[g * 12 + o];
    for (int ci = 0; ci < CCH; ci++) {
        float v = dc[base + (size_t)ci * SVOL];
        const float* wr = wt + ci * CCH + g * 12;
        #pragma unroll
        for (int o = 0; o < 12; o++) acc[o] += wr[o] * v;
    }
    #pragma unroll
    for (int o = 0; o < 12; o++) acc[o] *= u[base + (size_t)(g * 12 + o) * SVOL];
    half2_t* ap = a2p + ((size_t)b * 24 + g * 6) * SVOL + s;
    #pragma unroll
    for (int j = 0; j < 6; j++)
        ap[(size_t)j * SVOL] = half2_t{ (_Float16)acc[2 * j], (_Float16)acc[2 * j + 1] };
}

// ---- gate2: skip = x + gamma*(p2 . a2 + p2b + xn); writes fp32 skip + channel-last skh ----
__global__ __launch_bounds__(256, 4)
void gate2_kernel(const half2_t* __restrict__ a2p, const float* __restrict__ xn,
                  const float* __restrict__ x,
                  const half2_t* __restrict__ wt, const float* __restrict__ p2b,
                  const float* __restrict__ gamma, float* __restrict__ skip,
                  __half* __restrict__ skh) {
    int tid = threadIdx.x;
    int g = blockIdx.y, b = blockIdx.z;
    int s = blockIdx.x * 256 + tid;
    size_t base = (size_t)b * CCH * SVOL + s;
    const half2_t* ab = a2p + (size_t)b * 24 * SVOL + s;
    float acc[12];
    #pragma unroll
    for (int o = 0; o < 12; o++) acc[o] = p2b[g * 12 + o];
    for (int cp = 0; cp < 24; cp++) {
        half2_t v2 = ab[(size_t)cp * SVOL];
        const half2_t* wr = wt + cp * CCH + g * 12;
        #pragma unroll
        for (int o = 0; o < 12; o++) acc[o] = dot2f(v2, wr[o], acc[o]);
    }
    float sv[12];
    #pragma unroll
    for (int o = 0; o < 12; o++) {
        int oc = g * 12 + o;
        float vv = acc[o] + xn[base + (size_t)oc * SVOL];
        sv[o] = x[base + (size_t)oc * SVOL] + gamma[oc] * vv;
        skip[base + (size_t)oc * SVOL] = sv[o];
    }
    half2_t* sh = reinterpret_cast<half2_t*>(skh + ((size_t)b * SVOL + s) * CCH + g * 12);
    #pragma unroll
    for (int j = 0; j < 6; j++)
        sh[j] = half2_t{ (_Float16)sv[2 * j], (_Float16)sv[2 * j + 1] };
}

// ---- pr_final: out = skip + pr(attn), fp16 dot2; reads channel-last attnh ----
__global__ __launch_bounds__(256, 4)
void pr_final_kernel(const __half* __restrict__ attnh, const float* __restrict__ skip,
                     const half2_t* __restrict__ wt, const float* __restrict__ prb,
                     float* __restrict__ out) {
    int tid = threadIdx.x;
    int g = blockIdx.y, b = blockIdx.z;
    int s = blockIdx.x * 256 + tid;
    size_t base = (size_t)b * CCH * SVOL + s;
    const half2_t* ab = reinterpret_cast<const half2_t*>(attnh + ((size_t)b * SVOL + s) * CCH);
    float acc[12];
    #pragma unroll
    for (int o = 0; o < 12; o++) acc[o] = prb[g * 12 + o];
    for (int cp = 0; cp < 24; cp++) {
        half2_t v2 = ab[cp];
        const half2_t* wr = wt + cp * CCH + g * 12;
        #pragma unroll
        for (int o = 0; o < 12; o++) acc[o] = dot2f(v2, wr[o], acc[o]);
    }
    #pragma unroll
    for (int o = 0; o < 12; o++) {
        int oc = g * 12 + o;
        out[base + (size_t)oc * SVOL] = skip[base + (size_t)oc * SVOL] + acc[o];
    }
}

extern "C" void kernel_launch(void* const* d_in, const int* in_sizes, int n_in,
                              void* d_out, int out_size, void* d_ws, size_t ws_size,
                              hipStream_t stream) {
    (void)in_sizes; (void)n_in; (void)out_size; (void)ws_size;
    const float* x     = (const float*)d_in[0];
    const float* ln_s  = (const float*)d_in[1];
    const float* ln_b  = (const float*)d_in[2];
    const float* gamma = (const float*)d_in[3];
    const float* p1_w  = (const float*)d_in[4];
    const float* p1_b  = (const float*)d_in[5];
    const float* p2_w  = (const float*)d_in[6];
    const float* p2_b  = (const float*)d_in[7];
    const float* c0_w  = (const float*)d_in[8];
    const float* c0_b  = (const float*)d_in[9];
    const float* cs_w  = (const float*)d_in[10];
    const float* cs_b  = (const float*)d_in[11];
    const float* off_w = (const float*)d_in[12];
    const float* off_b = (const float*)d_in[13];
    const float* dc_w  = (const float*)d_in[14];
    const float* dc_b  = (const float*)d_in[15];
    const float* c1_w  = (const float*)d_in[16];
    const float* c1_b  = (const float*)d_in[17];
    const float* u1_w  = (const float*)d_in[18];
    const float* bn1_s = (const float*)d_in[19];
    const float* bn1_b = (const float*)d_in[20];
    const float* bn1_m = (const float*)d_in[21];
    const float* bn1_v = (const float*)d_in[22];
    const float* u2_w  = (const float*)d_in[23];
    const float* bn2_s = (const float*)d_in[24];
    const float* bn2_b = (const float*)d_in[25];
    const float* bn2_m = (const float*)d_in[26];
    const float* bn2_v = (const float*)d_in[27];
    const float* pr_w  = (const float*)d_in[28];
    const float* pr_b  = (const float*)d_in[29];
    float* out = (float*)d_out;

    float* wsf = (float*)d_ws;
    const size_t TS = (size_t)NB * CCH * SVOL;   // 3,145,728 floats
    float* xn   = out;            // d_out doubles as xn fp32 (dead after gate2)
    float* ubuf = wsf;            // u (gelu out fp32) -> [skh | h1h] (fp16 ch-last)
    float* bufA = wsf + TS;       // dw5 out -> a1h -> skip (fp32)
    float* bufB = wsf + 2 * TS;   // xnp (half2) -> dw7 out (a1) -> deform partials (dc)
    float* offb = wsf + 3 * TS;   // offsets [B,81,S] -> a2p (half2) -> attnh (fp16 ch-last)
    float* wtb    = wsf + 3 * TS + (size_t)NB * 81 * SVOL;
    float* wt_offf = wtb;                   // off MFMA A-frags: 31104 half4
    float* wt_dcf  = wt_offf + 104976;      // dc MFMA A-frags: 15552 half4
    float* wt_u1f  = wt_dcf + 62208;        // u1 MFMA A-frags: 15552 half4
    float* wt_u2f  = wt_u1f + 62208;        // u2 MFMA A-frags
    float* pt_p1  = wt_u2f + 62208;
    float* pt_c1  = pt_p1 + 2304;
    float* pt_p2  = pt_c1 + 2304;
    float* pt_pr  = pt_p2 + 2304;
    float* cb_all = pt_pr + 2304;

    __half*  a1h = (__half*)bufA;
    __half*  skh = (__half*)ubuf;                   // gate2 out (u dead)
    __half*  h1h = (__half*)(ubuf + TS / 2);        // u1 out
    half2_t* xnp = (half2_t*)bufB;
    half2_t* a2p = (half2_t*)offb;
    __half*  attnh = (__half*)offb;                 // a2p dead after gate2
    half4_t* wA_off = (half4_t*)wt_offf;
    half4_t* wA_dc  = (half4_t*)wt_dcf;
    half4_t* wA_u1 = (half4_t*)wt_u1f;
    half4_t* wA_u2 = (half4_t*)wt_u2f;
    half2_t* wt_p1h  = (half2_t*)pt_p1;
    half2_t* wt_p2h  = (half2_t*)pt_p2;
    half2_t* wt_prh  = (half2_t*)pt_pr;

    dim3 blk(256);
    dim3 gpos(SVOL / 256, NB);
    dim3 g4(SVOL / 256, 4, NB);
    dim3 gmf(512, NB);                 // MFMA conv kernels: 8x8x8 spatial tiles
    dim3 g3d(SVOL / 256, 3, NB);
    dim3 gdwc(8, CCH, NB);
    dim3 gtr(SVOL / 64, NB);

    hipLaunchKernelGGL(reshape_mfma_off_kernel, dim3((31104 + 255) / 256), blk, 0, stream, off_w, wA_off);
    hipLaunchKernelGGL(reshape_mfma48_kernel, dim3((15552 + 255) / 256), blk, 0, stream, u1_w, wA_u1);
    hipLaunchKernelGGL(reshape_mfma48_kernel, dim3((15552 + 255) / 256), blk, 0, stream, u2_w, wA_u2);
    hipLaunchKernelGGL(reshape_mfma_dc_kernel, dim3((15552 + 255) / 256), blk, 0, stream, dc_w, wA_dc);
    hipLaunchKernelGGL(t1x1_pair_kernel, dim3(5), blk, 0, stream, p1_w, wt_p1h);
    hipLaunchKernelGGL(t1x1_pair_kernel, dim3(5), blk, 0, stream, p2_w, wt_p2h);
    hipLaunchKernelGGL(t1x1_pair_kernel, dim3(5), blk, 0, stream, pr_w, wt_prh);
    hipLaunchKernelGGL(t1x1_kernel, dim3(9), blk, 0, stream, c1_w, pt_c1);
    hipLaunchKernelGGL(cb_kernel, dim3(1), dim3(64), 0, stream, c1_w, c1_b, dc_b, cb_all);

    hipLaunchKernelGGL(ln_kernel,            gpos, blk, 0, stream, x, ln_s, ln_b, xn, xnp);
    hipLaunchKernelGGL(p1_gelu_kernel,       g4,   blk, 0, stream, xnp, wt_p1h, p1_b, ubuf);
    hipLaunchKernelGGL(dw5_kernel,           gdwc, blk, 0, stream, ubuf, c0_w, c0_b, bufA);
    hipLaunchKernelGGL(dw7_kernel,           gdwc, blk, 0, stream, bufA, cs_w, cs_b, bufB);
    hipLaunchKernelGGL(transpose_pack_kernel, gtr, blk, 0, stream, bufB, a1h);
    hipLaunchKernelGGL(offconv_mfma_kernel,  gmf,  blk, 0, stream, a1h, wA_off, offb);
    hipMemsetAsync(bufB, 0, TS * sizeof(float), stream);
    hipLaunchKernelGGL(deform_mfma_kernel,   g3d,  blk, 0, stream, a1h, offb, off_b, wA_dc, bufB);
    hipLaunchKernelGGL(gate1_kernel,         g4,   blk, 0, stream, bufB, ubuf, pt_c1, cb_all, a2p);
    hipLaunchKernelGGL(gate2_kernel,         g4,   blk, 0, stream, a2p, xn, x, wt_p2h, p2_b, gamma,
                       bufA, skh);
    hipLaunchKernelGGL(u1_mfma_kernel,       gmf,  blk, 0, stream, skh, wA_u1,
                       bn1_s, bn1_b, bn1_m, bn1_v, h1h);
    hipLaunchKernelGGL(u2_mfma_kernel,       gmf,  blk, 0, stream, h1h, bufA, wA_u2,
                       bn2_s, bn2_b, bn2_m, bn2_v, attnh);
    hipLaunchKernelGGL(pr_final_kernel,      g4,   blk, 0, stream, attnh, bufA, wt_prh, pr_b, out);
}

// Round 27
// 482.940 us; speedup vs baseline: 1.2694x; 1.0007x over previous
//
#include <hip/hip_runtime.h>
#include <hip/hip_fp16.h>
#include <math.h>

#define CCH 48
#define SDIM 32
#define SVOL (SDIM*SDIM*SDIM)
#define NB 2

typedef _Float16 half2_t __attribute__((ext_vector_type(2)));
typedef _Float16 half4_t __attribute__((ext_vector_type(4)));
typedef float float4_t __attribute__((ext_vector_type(4)));

static __device__ __forceinline__ float dot2f(half2_t a, half2_t b, float c) {
#if __has_builtin(__builtin_amdgcn_fdot2)
    return __builtin_amdgcn_fdot2(a, b, c, false);
#else
    return c + (float)a[0] * (float)b[0] + (float)a[1] * (float)b[1];
#endif
}

// ======== one-off weight reshape kernels ========

__global__ __launch_bounds__(256)
void reshape_mfma_off_kernel(const float* __restrict__ w, half4_t* __restrict__ wA) {
    int e = blockIdx.x * 256 + threadIdx.x;
    if (e < 31104) {
        int row = e & 15;
        int kq = (e >> 4) & 3;
        int ks = (e / 64) % 3;
        int mt = (e / 192) % 6;
        int tap = e / 1152;
        int o = mt * 16 + row;
        half4_t v;
        #pragma unroll
        for (int h = 0; h < 4; h++) {
            int ci = ks * 16 + kq * 4 + h;
            float val = (o < 81) ? w[((size_t)o * CCH + ci) * 27 + tap] : 0.f;
            v[h] = (_Float16)val;
        }
        wA[e] = v;
    }
}

__global__ __launch_bounds__(256)
void reshape_mfma48_kernel(const float* __restrict__ w, half4_t* __restrict__ wA) {
    int e = blockIdx.x * 256 + threadIdx.x;
    if (e < 15552) {
        int row = e & 15;
        int kq = (e >> 4) & 3;
        int ks = (e / 64) % 3;
        int mt = (e / 192) % 3;
        int tap = e / 576;
        int o = mt * 16 + row;
        half4_t v;
        #pragma unroll
        for (int h = 0; h < 4; h++) {
            int ci = ks * 16 + kq * 4 + h;
            v[h] = (_Float16)w[((size_t)o * CCH + ci) * 27 + tap];
        }
        wA[e] = v;
    }
}

__global__ __launch_bounds__(256)
void reshape_mfma_dc_kernel(const float* __restrict__ w, half4_t* __restrict__ wA) {
    int e = blockIdx.x * 256 + threadIdx.x;
    if (e < 15552) {
        int row = e & 15;
        int kq = (e >> 4) & 3;
        int mt = (e / 64) % 3;
        int tap = (e / 192) % 27;
        int gc = e / 5184;
        int o = mt * 16 + row;
        half4_t v;
        #pragma unroll
        for (int h = 0; h < 4; h++) {
            int ci = gc * 16 + kq * 4 + h;
            v[h] = (_Float16)w[((size_t)o * CCH + ci) * 27 + tap];
        }
        wA[e] = v;
    }
}

__global__ __launch_bounds__(256)
void t1x1_pair_kernel(const float* __restrict__ w, half2_t* __restrict__ wt) {
    int i = blockIdx.x * 256 + threadIdx.x;
    if (i < 24 * CCH) {
        int o = i % CCH, cp = i / CCH;
        wt[i] = half2_t{ (_Float16)w[o * CCH + 2 * cp], (_Float16)w[o * CCH + 2 * cp + 1] };
    }
}

__global__ __launch_bounds__(256)
void t1x1_kernel(const float* __restrict__ w, float* __restrict__ wt) {
    int i = blockIdx.x * 256 + threadIdx.x;
    if (i < CCH * CCH) { int ci = i / CCH, o = i % CCH; wt[i] = w[o * CCH + ci]; }
}

__global__ __launch_bounds__(64)
void cb_kernel(const float* __restrict__ c1w, const float* __restrict__ c1b,
               const float* __restrict__ dcb, float* __restrict__ cb) {
    int o = threadIdx.x;
    if (o < CCH) {
        float v = c1b[o];
        for (int ci = 0; ci < CCH; ci++) v += c1w[o * CCH + ci] * dcb[ci];
        cb[o] = v;
    }
}

// ---------------- LayerNorm over C; writes fp32 xn AND half2-pair xnp ----------------
__global__ __launch_bounds__(256)
void ln_kernel(const float* __restrict__ x, const float* __restrict__ ln_s,
               const float* __restrict__ ln_b, float* __restrict__ xn,
               half2_t* __restrict__ xnp) {
    int s = blockIdx.x * 256 + threadIdx.x;
    int b = blockIdx.y;
    const float* xb = x + (size_t)b * CCH * SVOL + s;
    float v[CCH];
    float mu = 0.f;
    #pragma unroll
    for (int c = 0; c < CCH; c++) { v[c] = xb[c * SVOL]; mu += v[c]; }
    mu *= (1.0f / CCH);
    float var = 0.f;
    #pragma unroll
    for (int c = 0; c < CCH; c++) { float d = v[c] - mu; var += d * d; }
    var *= (1.0f / CCH);
    float inv = rsqrtf(var + 1e-5f);
    float* o = xn + (size_t)b * CCH * SVOL + s;
    float nv[CCH];
    #pragma unroll
    for (int c = 0; c < CCH; c++) { nv[c] = (v[c] - mu) * inv * ln_s[c] + ln_b[c]; o[c * SVOL] = nv[c]; }
    half2_t* xp = xnp + (size_t)b * 24 * SVOL + s;
    #pragma unroll
    for (int cp = 0; cp < 24; cp++)
        xp[(size_t)cp * SVOL] = half2_t{ (_Float16)nv[2 * cp], (_Float16)nv[2 * cp + 1] };
}

// ---------------- 1x1x1 conv + exact GELU (4 groups x 12), fp16 dot2 ----------------
__global__ __launch_bounds__(256, 4)
void p1_gelu_kernel(const half2_t* __restrict__ xnp, const half2_t* __restrict__ wt,
                    const float* __restrict__ bias, float* __restrict__ u) {
    int tid = threadIdx.x;
    int g = blockIdx.y, b = blockIdx.z;
    int s = blockIdx.x * 256 + tid;
    const half2_t* xb = xnp + (size_t)b * 24 * SVOL + s;
    float acc[12];
    #pragma unroll
    for (int o = 0; o < 12; o++) acc[o] = bias[g * 12 + o];
    for (int cp = 0; cp < 24; cp++) {
        half2_t v2 = xb[(size_t)cp * SVOL];
        const half2_t* wr = wt + cp * CCH + g * 12;
        #pragma unroll
        for (int o = 0; o < 12; o++) acc[o] = dot2f(v2, wr[o], acc[o]);
    }
    float* ub = u + (size_t)b * CCH * SVOL + s + (size_t)(g * 12) * SVOL;
    #pragma unroll
    for (int o = 0; o < 12; o++) {
        float a = acc[o];
        ub[o * SVOL] = 0.5f * a * (1.0f + erff(a * 0.70710678118654752f));
    }
}

// ---- depthwise 5x5x5 pad 2: half-column blocking (16 z/thread, window cache) ----
__global__ __launch_bounds__(256, 4)
void dw5_kernel(const float* __restrict__ in, const float* __restrict__ w,
                const float* __restrict__ bias, float* __restrict__ out) {
    int tid = threadIdx.x;
    int c = blockIdx.y, b = blockIdx.z;
    const float* wc = w + c * 125;
    int bx = blockIdx.x;
    int yx = (bx >> 1) * 256 + tid;
    int z0 = (bx & 1) * 16;
    int y = yx >> 5, xx = yx & 31;
    const float* ib = in + ((size_t)b * CCH + c) * SVOL;
    float acc[16];
    float bv = bias[c];
    #pragma unroll
    for (int z = 0; z < 16; z++) acc[z] = bv;
    for (int ty = 0; ty < 5; ty++) {
        int yy = y + ty - 2; if (yy < 0 || yy >= 32) continue;
        for (int tx = 0; tx < 5; tx++) {
            int xv = xx + tx - 2; if (xv < 0 || xv >= 32) continue;
            const float* col = ib + yy * 32 + xv;
            float cv[20];
            #pragma unroll
            for (int j = 0; j < 20; j++) {
                int zz = z0 - 2 + j;
                cv[j] = (zz >= 0 && zz < 32) ? col[(size_t)zz * 1024] : 0.f;
            }
            #pragma unroll
            for (int tz = 0; tz < 5; tz++) {
                float wv = wc[(tz * 5 + ty) * 5 + tx];
                #pragma unroll
                for (int z = 0; z < 16; z++) acc[z] += wv * cv[z + tz];
            }
        }
    }
    float* ob = out + ((size_t)b * CCH + c) * SVOL + y * 32 + xx;
    #pragma unroll
    for (int z = 0; z < 16; z++) ob[(size_t)(z0 + z) * 1024] = acc[z];
}

// ---- depthwise 7x7x7 dil 3 pad 9: half-column blocking (16 z/thread, window cache) ----
__global__ __launch_bounds__(256, 4)
void dw7_kernel(const float* __restrict__ in, const float* __restrict__ w,
                const float* __restrict__ bias, float* __restrict__ out) {
    int tid = threadIdx.x;
    int c = blockIdx.y, b = blockIdx.z;
    const float* wc = w + c * 343;
    int bx = blockIdx.x;
    int yx = (bx >> 1) * 256 + tid;
    int z0 = (bx & 1) * 16;
    int y = yx >> 5, xx = yx & 31;
    const float* ib = in + ((size_t)b * CCH + c) * SVOL;
    float acc[16];
    float bv = bias[c];
    #pragma unroll
    for (int z = 0; z < 16; z++) acc[z] = bv;
    for (int ty = 0; ty < 7; ty++) {
        int yy = y + 3 * (ty - 3); if (yy < 0 || yy >= 32) continue;
        for (int tx = 0; tx < 7; tx++) {
            int xv = xx + 3 * (tx - 3); if (xv < 0 || xv >= 32) continue;
            const float* col = ib + yy * 32 + xv;
            float cv[34];
            #pragma unroll
            for (int j = 0; j < 34; j++) {
                int zz = z0 - 9 + j;
                cv[j] = (zz >= 0 && zz < 32) ? col[(size_t)zz * 1024] : 0.f;
            }
            #pragma unroll
            for (int tz = 0; tz < 7; tz++) {
                float wv = wc[(tz * 7 + ty) * 7 + tx];
                #pragma unroll
                for (int z = 0; z < 16; z++) acc[z] += wv * cv[z + 3 * tz];
            }
        }
    }
    float* ob = out + ((size_t)b * CCH + c) * SVOL + y * 32 + xx;
    #pragma unroll
    for (int z = 0; z < 16; z++) ob[(size_t)(z0 + z) * 1024] = acc[z];
}

// ---- a1 fp32 [48][S] -> a1h fp16 [S][48] ----
__global__ __launch_bounds__(256)
void transpose_pack_kernel(const float* __restrict__ a1, __half* __restrict__ a1h) {
    __shared__ float tile[CCH * 65];
    int tid = threadIdx.x;
    int b = blockIdx.y;
    int s0 = blockIdx.x * 64;
    const float* ib = a1 + (size_t)b * CCH * SVOL + s0;
    for (int i = tid; i < CCH * 64; i += 256) {
        int c = i >> 6, p = i & 63;
        tile[c * 65 + p] = ib[(size_t)c * SVOL + p];
    }
    __syncthreads();
    __half* ob = a1h + ((size_t)b * SVOL + s0) * CCH;
    for (int i = tid; i < 64 * CCH; i += 256) {
        int p = i / CCH, c = i % CCH;
        ob[i] = __float2half(tile[c * 65 + p]);
    }
}

// ---- offset conv 3x3x3 via MFMA implicit-GEMM: 4x4x4 tile, halo in LDS, no atomics ----
__global__ __launch_bounds__(256, 4)
void offconv_mfma_kernel(const __half* __restrict__ a1h, const half4_t* __restrict__ wA,
                         float* __restrict__ off) {
    __shared__ __half halo[216 * 52];
    int tid = threadIdx.x;
    int t = blockIdx.x;
    int b = blockIdx.y;
    int tz0 = (t >> 6) * 4, ty0 = ((t >> 3) & 7) * 4, tx0 = (t & 7) * 4;
    const __half* ab = a1h + (size_t)b * SVOL * CCH;
    for (int idx = tid; idx < 216 * 24; idx += 256) {
        int hpos = idx / 24, kp = idx % 24;
        int hz = hpos / 36, hy = (hpos / 6) % 6, hx = hpos % 6;
        int gz = tz0 + hz - 1, gy = ty0 + hy - 1, gx = tx0 + hx - 1;
        unsigned int v = 0u;
        if (gz >= 0 && gz < 32 && gy >= 0 && gy < 32 && gx >= 0 && gx < 32) {
            int s = (gz * 32 + gy) * 32 + gx;
            v = *reinterpret_cast<const unsigned int*>(ab + (size_t)s * CCH + kp * 2);
        }
        *reinterpret_cast<unsigned int*>(&halo[hpos * 52 + kp * 2]) = v;
    }
    __syncthreads();
    int wave = tid >> 6, lane = tid & 63;
    int col = lane & 15;
    int kq = lane >> 4;
    int py = col >> 2, px = col & 3;
    int pz = wave;
    float4_t acc[6];
    #pragma unroll
    for (int m = 0; m < 6; m++) acc[m] = (float4_t)0.f;
    for (int tap = 0; tap < 27; tap++) {
        int dz = tap / 9, dy = (tap / 3) % 3, dx = tap % 3;
        int hbase = ((pz + dz) * 36 + (py + dy) * 6 + (px + dx)) * 52 + kq * 4;
        half4_t bf0 = *reinterpret_cast<const half4_t*>(&halo[hbase]);
        half4_t bf1 = *reinterpret_cast<const half4_t*>(&halo[hbase + 16]);
        half4_t bf2 = *reinterpret_cast<const half4_t*>(&halo[hbase + 32]);
        #pragma unroll
        for (int mt = 0; mt < 6; mt++) {
            int fb = (tap * 6 + mt) * 12 + kq;
            half4_t a0 = wA[(size_t)fb * 16 + col];
            half4_t a1 = wA[(size_t)(fb + 4) * 16 + col];
            half4_t a2 = wA[(size_t)(fb + 8) * 16 + col];
            acc[mt] = __builtin_amdgcn_mfma_f32_16x16x16f16(a0, bf0, acc[mt], 0, 0, 0);
            acc[mt] = __builtin_amdgcn_mfma_f32_16x16x16f16(a1, bf1, acc[mt], 0, 0, 0);
            acc[mt] = __builtin_amdgcn_mfma_f32_16x16x16f16(a2, bf2, acc[mt], 0, 0, 0);
        }
    }
    int sg = ((tz0 + pz) * 32 + ty0 + py) * 32 + tx0 + px;
    float* ob = off + (size_t)b * 81 * SVOL + sg;
    #pragma unroll
    for (int mt = 0; mt < 6; mt++) {
        #pragma unroll
        for (int r = 0; r < 4; r++) {
            int orow = mt * 16 + kq * 4 + r;
            if (orow < 81) ob[(size_t)orow * SVOL] = acc[mt][r];
        }
    }
}

// ---- u1 3x3x3 via MFMA + BN1 + LeakyReLU; in: skh [S][48] fp16, out: h1h [S][48] fp16 ----
__global__ __launch_bounds__(256, 4)
void u1_mfma_kernel(const __half* __restrict__ skh, const half4_t* __restrict__ wA,
                    const float* __restrict__ bs, const float* __restrict__ bb,
                    const float* __restrict__ bm, const float* __restrict__ bv,
                    __half* __restrict__ h1h) {
    __shared__ __half halo[216 * 52];
    int tid = threadIdx.x;
    int t = blockIdx.x;
    int b = blockIdx.y;
    int tz0 = (t >> 6) * 4, ty0 = ((t >> 3) & 7) * 4, tx0 = (t & 7) * 4;
    const __half* ab = skh + (size_t)b * SVOL * CCH;
    for (int idx = tid; idx < 216 * 24; idx += 256) {
        int hpos = idx / 24, kp = idx % 24;
        int hz = hpos / 36, hy = (hpos / 6) % 6, hx = hpos % 6;
        int gz = tz0 + hz - 1, gy = ty0 + hy - 1, gx = tx0 + hx - 1;
        unsigned int v = 0u;
        if (gz >= 0 && gz < 32 && gy >= 0 && gy < 32 && gx >= 0 && gx < 32) {
            int s = (gz * 32 + gy) * 32 + gx;
            v = *reinterpret_cast<const unsigned int*>(ab + (size_t)s * CCH + kp * 2);
        }
        *reinterpret_cast<unsigned int*>(&halo[hpos * 52 + kp * 2]) = v;
    }
    __syncthreads();
    int wave = tid >> 6, lane = tid & 63;
    int col = lane & 15;
    int kq = lane >> 4;
    int py = col >> 2, px = col & 3;
    int pz = wave;
    float4_t acc[3];
    #pragma unroll
    for (int m = 0; m < 3; m++) acc[m] = (float4_t)0.f;
    for (int tap = 0; tap < 27; tap++) {
        int dz = tap / 9, dy = (tap / 3) % 3, dx = tap % 3;
        int hbase = ((pz + dz) * 36 + (py + dy) * 6 + (px + dx)) * 52 + kq * 4;
        half4_t bf0 = *reinterpret_cast<const half4_t*>(&halo[hbase]);
        half4_t bf1 = *reinterpret_cast<const half4_t*>(&halo[hbase + 16]);
        half4_t bf2 = *reinterpret_cast<const half4_t*>(&halo[hbase + 32]);
        #pragma unroll
        for (int mt = 0; mt < 3; mt++) {
            int fb = (tap * 3 + mt) * 12 + kq;
            half4_t a0 = wA[(size_t)fb * 16 + col];
            half4_t a1 = wA[(size_t)(fb + 4) * 16 + col];
            half4_t a2 = wA[(size_t)(fb + 8) * 16 + col];
            acc[mt] = __builtin_amdgcn_mfma_f32_16x16x16f16(a0, bf0, acc[mt], 0, 0, 0);
            acc[mt] = __builtin_amdgcn_mfma_f32_16x16x16f16(a1, bf1, acc[mt], 0, 0, 0);
            acc[mt] = __builtin_amdgcn_mfma_f32_16x16x16f16(a2, bf2, acc[mt], 0, 0, 0);
        }
    }
    int sg = ((tz0 + pz) * 32 + ty0 + py) * 32 + tx0 + px;
    __half* ob = h1h + ((size_t)b * SVOL + sg) * CCH;
    #pragma unroll
    for (int mt = 0; mt < 3; mt++) {
        float hv[4];
        #pragma unroll
        for (int r = 0; r < 4; r++) {
            int orow = mt * 16 + kq * 4 + r;
            float inv = rsqrtf(bv[orow] + 1e-5f);
            float h = (acc[mt][r] - bm[orow]) * (bs[orow] * inv) + bb[orow];
            hv[r] = h >= 0.f ? h : 0.01f * h;
        }
        half2_t* po = reinterpret_cast<half2_t*>(ob + mt * 16 + kq * 4);
        po[0] = half2_t{ (_Float16)hv[0], (_Float16)hv[1] };
        po[1] = half2_t{ (_Float16)hv[2], (_Float16)hv[3] };
    }
}

// ---- u2 3x3x3 via MFMA + BN2 + (+skip fp32) + LeakyReLU; out: attnh [S][48] fp16 ----
__global__ __launch_bounds__(256, 4)
void u2_mfma_kernel(const __half* __restrict__ h1h, const float* __restrict__ skip,
                    const half4_t* __restrict__ wA,
                    const float* __restrict__ bs, const float* __restrict__ bb,
                    const float* __restrict__ bm, const float* __restrict__ bv,
                    __half* __restrict__ attnh) {
    __shared__ __half halo[216 * 52];
    int tid = threadIdx.x;
    int t = blockIdx.x;
    int b = blockIdx.y;
    int tz0 = (t >> 6) * 4, ty0 = ((t >> 3) & 7) * 4, tx0 = (t & 7) * 4;
    const __half* ab = h1h + (size_t)b * SVOL * CCH;
    for (int idx = tid; idx < 216 * 24; idx += 256) {
        int hpos = idx / 24, kp = idx % 24;
        int hz = hpos / 36, hy = (hpos / 6) % 6, hx = hpos % 6;
        int gz = tz0 + hz - 1, gy = ty0 + hy - 1, gx = tx0 + hx - 1;
        unsigned int v = 0u;
        if (gz >= 0 && gz < 32 && gy >= 0 && gy < 32 && gx >= 0 && gx < 32) {
            int s = (gz * 32 + gy) * 32 + gx;
            v = *reinterpret_cast<const unsigned int*>(ab + (size_t)s * CCH + kp * 2);
        }
        *reinterpret_cast<unsigned int*>(&halo[hpos * 52 + kp * 2]) = v;
    }
    __syncthreads();
    int wave = tid >> 6, lane = tid & 63;
    int col = lane & 15;
    int kq = lane >> 4;
    int py = col >> 2, px = col & 3;
    int pz = wave;
    float4_t acc[3];
    #pragma unroll
    for (int m = 0; m < 3; m++) acc[m] = (float4_t)0.f;
    for (int tap = 0; tap < 27; tap++) {
        int dz = tap / 9, dy = (tap / 3) % 3, dx = tap % 3;
        int hbase = ((pz + dz) * 36 + (py + dy) * 6 + (px + dx)) * 52 + kq * 4;
        half4_t bf0 = *reinterpret_cast<const half4_t*>(&halo[hbase]);
        half4_t bf1 = *reinterpret_cast<const half4_t*>(&halo[hbase + 16]);
        half4_t bf2 = *reinterpret_cast<const half4_t*>(&halo[hbase + 32]);
        #pragma unroll
        for (int mt = 0; mt < 3; mt++) {
            int fb = (tap * 3 + mt) * 12 + kq;
            half4_t a0 = wA[(size_t)fb * 16 + col];
            half4_t a1 = wA[(size_t)(fb + 4) * 16 + col];
            half4_t a2 = wA[(size_t)(fb + 8) * 16 + col];
            acc[mt] = __builtin_amdgcn_mfma_f32_16x16x16f16(a0, bf0, acc[mt], 0, 0, 0);
            acc[mt] = __builtin_amdgcn_mfma_f32_16x16x16f16(a1, bf1, acc[mt], 0, 0, 0);
            acc[mt] = __builtin_amdgcn_mfma_f32_16x16x16f16(a2, bf2, acc[mt], 0, 0, 0);
        }
    }
    int sg = ((tz0 + pz) * 32 + ty0 + py) * 32 + tx0 + px;
    const float* sk = skip + (size_t)b * CCH * SVOL + sg;
    __half* ob = attnh + ((size_t)b * SVOL + sg) * CCH;
    #pragma unroll
    for (int mt = 0; mt < 3; mt++) {
        float av[4];
        #pragma unroll
        for (int r = 0; r < 4; r++) {
            int orow = mt * 16 + kq * 4 + r;
            float inv = rsqrtf(bv[orow] + 1e-5f);
            float h = (acc[mt][r] - bm[orow]) * (bs[orow] * inv) + bb[orow];
            float a = h + sk[(size_t)orow * SVOL];
            av[r] = a >= 0.f ? a : 0.01f * a;
        }
        half2_t* po = reinterpret_cast<half2_t*>(ob + mt * 16 + kq * 4);
        po[0] = half2_t{ (_Float16)av[0], (_Float16)av[1] };
        po[1] = half2_t{ (_Float16)av[2], (_Float16)av[3] };
    }
}

// ---- deformable conv 3x3x3: ci-split 3, fp16 interp + MFMA, 1-wave blocks (occupancy) ----
struct h8v { half2_t a, b, c, d; };   // 16 bytes = 8 halves

__global__ __launch_bounds__(64)
void deform_mfma_kernel(const __half* __restrict__ a1h, const float* __restrict__ off,
                        const float* __restrict__ off_b,
                        const half4_t* __restrict__ wA, float* __restrict__ out) {
    __shared__ __half vbuf[2][64][20];   // [parity][pos][16ch + 4 pad] = 5 KB
    int lane = threadIdx.x;
    int gc = blockIdx.y;            // ci group 0..2 (16 ch)
    int b = blockIdx.z;
    int col = lane & 15, kq = lane >> 4;
    int s = blockIdx.x * 64 + lane;
    int z = s >> 10, y = (s >> 5) & 31, xx = s & 31;
    const __half* abase = a1h + (size_t)b * SVOL * CCH + gc * 16;
    const float* ob = off + (size_t)b * 81 * SVOL + s;
    float4_t acc[3][4];
    #pragma unroll
    for (int m = 0; m < 3; m++)
        #pragma unroll
        for (int c = 0; c < 4; c++) acc[m][c] = (float4_t)0.f;
    for (int k = 0; k < 27; k++) {
        int kd = k / 9 - 1, kh = (k / 3) % 3 - 1, kw = k % 3 - 1;
        float zf = (float)(z + kd) + ob[(size_t)(k * 3 + 0) * SVOL] + off_b[k * 3 + 0];
        float yf = (float)(y + kh) + ob[(size_t)(k * 3 + 1) * SVOL] + off_b[k * 3 + 1];
        float xf = (float)(xx + kw) + ob[(size_t)(k * 3 + 2) * SVOL] + off_b[k * 3 + 2];
        float z0 = floorf(zf), y0 = floorf(yf), x0 = floorf(xf);
        float tz = zf - z0, ty = yf - y0, tx = xf - x0;
        int iz0 = (int)z0, iy0 = (int)y0, ix0 = (int)x0;
        half2_t val2[8];
        #pragma unroll
        for (int j = 0; j < 8; j++) val2[j] = (half2_t)(_Float16)0;
        #pragma unroll
        for (int corner = 0; corner < 8; corner++) {
            int dz = corner >> 2, dy = (corner >> 1) & 1, dx = corner & 1;
            int zi = iz0 + dz, yi = iy0 + dy, xi = ix0 + dx;
            bool valid = (zi >= 0 && zi < 32 && yi >= 0 && yi < 32 && xi >= 0 && xi < 32);
            float wgt = (dz ? tz : 1.f - tz) * (dy ? ty : 1.f - ty) * (dx ? tx : 1.f - tx);
            float cwv = valid ? wgt : 0.f;
            _Float16 cwh = (_Float16)cwv;
            half2_t cw2 = { cwh, cwh };
            int zc = min(max(zi, 0), 31), yc = min(max(yi, 0), 31), xc = min(max(xi, 0), 31);
            int cidx = (zc * 32 + yc) * 32 + xc;
            const h8v* pv = (const h8v*)(abase + (size_t)cidx * CCH);
            h8v q0 = pv[0], q1 = pv[1];
            val2[0] += cw2 * q0.a;  val2[1] += cw2 * q0.b;
            val2[2] += cw2 * q0.c;  val2[3] += cw2 * q0.d;
            val2[4] += cw2 * q1.a;  val2[5] += cw2 * q1.b;
            val2[6] += cw2 * q1.c;  val2[7] += cw2 * q1.d;
        }
        // stage 16 interpolated channels into wave-private LDS (parity double-buffer)
        __half* vb = &vbuf[k & 1][lane][0];
        half4_t* vb4 = reinterpret_cast<half4_t*>(vb);
        vb4[0] = half4_t{ val2[0][0], val2[0][1], val2[1][0], val2[1][1] };
        vb4[1] = half4_t{ val2[2][0], val2[2][1], val2[3][0], val2[3][1] };
        vb4[2] = half4_t{ val2[4][0], val2[4][1], val2[5][0], val2[5][1] };
        vb4[3] = half4_t{ val2[6][0], val2[6][1], val2[7][0], val2[7][1] };
        // A fragments for this tap (reused across 4 col-tiles)
        half4_t a0, a1, a2;
        {
            int fb = ((gc * 27 + k) * 3 + 0) * 4 + kq;
            a0 = wA[(size_t)fb * 16 + col];
            a1 = wA[(size_t)(fb + 4) * 16 + col];
            a2 = wA[(size_t)(fb + 8) * 16 + col];
        }
        #pragma unroll
        for (int ct = 0; ct < 4; ct++) {
            half4_t bf = *reinterpret_cast<const half4_t*>(&vbuf[k & 1][ct * 16 + col][kq * 4]);
            acc[0][ct] = __builtin_amdgcn_mfma_f32_16x16x16f16(a0, bf, acc[0][ct], 0, 0, 0);
            acc[1][ct] = __builtin_amdgcn_mfma_f32_16x16x16f16(a1, bf, acc[1][ct], 0, 0, 0);
            acc[2][ct] = __builtin_amdgcn_mfma_f32_16x16x16f16(a2, bf, acc[2][ct], 0, 0, 0);
        }
    }
    int sbase = blockIdx.x * 64;
    float* op = out + (size_t)b * CCH * SVOL;
    #pragma unroll
    for (int mt = 0; mt < 3; mt++) {
        #pragma unroll
        for (int ct = 0; ct < 4; ct++) {
            int sp = sbase + ct * 16 + col;
            #pragma unroll
            for (int r = 0; r < 4; r++) {
                int o = mt * 16 + kq * 4 + r;
                atomicAdd(&op[(size_t)o * SVOL + sp], acc[mt][ct][r]);
            }
        }
    }
}

// ---- gate1: a2 = (c1 . dc + cb) * u; writes half2-pair a2p ----
__global__ __launch_bounds__(256, 4)
void gate1_kernel(const float* __restrict__ dc, const float* __restrict__ u,
                  const float* __restrict__ wt, const float* __restrict__ cb,
                  half2_t* __restrict__ a2p) {
    int tid = threadIdx.x;
    int g = blockIdx.y, b = blockIdx.z;
    int s = blockIdx.x * 256 + tid;
    size_t base = (size_t)b * CCH * SVOL + s;
    float acc[12];
    #pragma unroll
    for (int o = 0; o < 12; o++) acc[o] = cb[g * 12 + o];
    for (int ci = 0; ci < CCH; ci++) {
        float v = dc[base + (size_t)ci * SVOL];
        const float* wr = wt + ci * CCH + g * 12;
        #pragma unroll
        for (int o = 0; o < 12; o++) acc[o] += wr[o] * v;
    }
    #pragma unroll
    for (int o = 0; o < 12; o++) acc[o] *= u[base + (size_t)(g * 12 + o) * SVOL];
    half2_t* ap = a2p + ((size_t)b * 24 + g * 6) * SVOL + s;
    #pragma unroll
    for (int j = 0; j < 6; j++)
        ap[(size_t)j * SVOL] = half2_t{ (_Float16)acc[2 * j], (_Float16)acc[2 * j + 1] };
}

// ---- gate2: skip = x + gamma*(p2 . a2 + p2b + xn); writes fp32 skip + channel-last skh ----
__global__ __launch_bounds__(256, 4)
void gate2_kernel(const half2_t* __restrict__ a2p, const float* __restrict__ xn,
                  const float* __restrict__ x,
                  const half2_t* __restrict__ wt, const float* __restrict__ p2b,
                  const float* __restrict__ gamma, float* __restrict__ skip,
                  __half* __restrict__ skh) {
    int tid = threadIdx.x;
    int g = blockIdx.y, b = blockIdx.z;
    int s = blockIdx.x * 256 + tid;
    size_t base = (size_t)b * CCH * SVOL + s;
    const half2_t* ab = a2p + (size_t)b * 24 * SVOL + s;
    float acc[12];
    #pragma unroll
    for (int o = 0; o < 12; o++) acc[o] = p2b[g * 12 + o];
    for (int cp = 0; cp < 24; cp++) {
        half2_t v2 = ab[(size_t)cp * SVOL];
        const half2_t* wr = wt + cp * CCH + g * 12;
        #pragma unroll
        for (int o = 0; o < 12; o++) acc[o] = dot2f(v2, wr[o], acc[o]);
    }
    float sv[12];
    #pragma unroll
    for (int o = 0; o < 12; o++) {
        int oc = g * 12 + o;
        float vv = acc[o] + xn[base + (size_t)oc * SVOL];
        sv[o] = x[base + (size_t)oc * SVOL] + gamma[oc] * vv;
        skip[base + (size_t)oc * SVOL] = sv[o];
    }
    half2_t* sh = reinterpret_cast<half2_t*>(skh + ((size_t)b * SVOL + s) * CCH + g * 12);
    #pragma unroll
    for (int j = 0; j < 6; j++)
        sh[j] = half2_t{ (_Float16)sv[2 * j], (_Float16)sv[2 * j + 1] };
}

// ---- pr_final: out = skip + pr(attn), fp16 dot2; reads channel-last attnh ----
__global__ __launch_bounds__(256, 4)
void pr_final_kernel(const __half* __restrict__ attnh, const float* __restrict__ skip,
                     const half2_t* __restrict__ wt, const float* __restrict__ prb,
                     float* __restrict__ out) {
    int tid = threadIdx.x;
    int g = blockIdx.y, b = blockIdx.z;
    int s = blockIdx.x * 256 + tid;
    size_t base = (size_t)b * CCH * SVOL + s;
    const half2_t* ab = reinterpret_cast<const half2_t*>(attnh + ((size_t)b * SVOL + s) * CCH);
    float acc[12];
    #pragma unroll
    for (int o = 0; o < 12; o++) acc[o] = prb[g * 12 + o];
    for (int cp = 0; cp < 24; cp++) {
        half2_t v2 = ab[cp];
        const half2_t* wr = wt + cp * CCH + g * 12;
        #pragma unroll
        for (int o = 0; o < 12; o++) acc[o] = dot2f(v2, wr[o], acc[o]);
    }
    #pragma unroll
    for (int o = 0; o < 12; o++) {
        int oc = g * 12 + o;
        out[base + (size_t)oc * SVOL] = skip[base + (size_t)oc * SVOL] + acc[o];
    }
}

extern "C" void kernel_launch(void* const* d_in, const int* in_sizes, int n_in,
                              void* d_out, int out_size, void* d_ws, size_t ws_size,
                              hipStream_t stream) {
    (void)in_sizes; (void)n_in; (void)out_size; (void)ws_size;
    const float* x     = (const float*)d_in[0];
    const float* ln_s  = (const float*)d_in[1];
    const float* ln_b  = (const float*)d_in[2];
    const float* gamma = (const float*)d_in[3];
    const float* p1_w  = (const float*)d_in[4];
    const float* p1_b  = (const float*)d_in[5];
    const float* p2_w  = (const float*)d_in[6];
    const float* p2_b  = (const float*)d_in[7];
    const float* c0_w  = (const float*)d_in[8];
    const float* c0_b  = (const float*)d_in[9];
    const float* cs_w  = (const float*)d_in[10];
    const float* cs_b  = (const float*)d_in[11];
    const float* off_w = (const float*)d_in[12];
    const float* off_b = (const float*)d_in[13];
    const float* dc_w  = (const float*)d_in[14];
    const float* dc_b  = (const float*)d_in[15];
    const float* c1_w  = (const float*)d_in[16];
    const float* c1_b  = (const float*)d_in[17];
    const float* u1_w  = (const float*)d_in[18];
    const float* bn1_s = (const float*)d_in[19];
    const float* bn1_b = (const float*)d_in[20];
    const float* bn1_m = (const float*)d_in[21];
    const float* bn1_v = (const float*)d_in[22];
    const float* u2_w  = (const float*)d_in[23];
    const float* bn2_s = (const float*)d_in[24];
    const float* bn2_b = (const float*)d_in[25];
    const float* bn2_m = (const float*)d_in[26];
    const float* bn2_v = (const float*)d_in[27];
    const float* pr_w  = (const float*)d_in[28];
    const float* pr_b  = (const float*)d_in[29];
    float* out = (float*)d_out;

    float* wsf = (float*)d_ws;
    const size_t TS = (size_t)NB * CCH * SVOL;   // 3,145,728 floats
    float* xn   = out;            // d_out doubles as xn fp32 (dead after gate2)
    float* ubuf = wsf;            // u (gelu out fp32) -> [skh | h1h] (fp16 ch-last)
    float* bufA = wsf + TS;       // dw5 out -> a1h -> skip (fp32)
    float* bufB = wsf + 2 * TS;   // xnp (half2) -> dw7 out (a1) -> deform partials (dc)
    float* offb = wsf + 3 * TS;   // offsets [B,81,S] -> a2p (half2) -> attnh (fp16 ch-last)
    float* wtb    = wsf + 3 * TS + (size_t)NB * 81 * SVOL;
    float* wt_offf = wtb;                   // off MFMA A-frags: 31104 half4
    float* wt_dcf  = wt_offf + 104976;      // dc MFMA A-frags: 15552 half4
    float* wt_u1f  = wt_dcf + 62208;        // u1 MFMA A-frags: 15552 half4
    float* wt_u2f  = wt_u1f + 62208;        // u2 MFMA A-frags
    float* pt_p1  = wt_u2f + 62208;
    float* pt_c1  = pt_p1 + 2304;
    float* pt_p2  = pt_c1 + 2304;
    float* pt_pr  = pt_p2 + 2304;
    float* cb_all = pt_pr + 2304;

    __half*  a1h = (__half*)bufA;
    __half*  skh = (__half*)ubuf;                   // gate2 out (u dead)
    __half*  h1h = (__half*)(ubuf + TS / 2);        // u1 out
    half2_t* xnp = (half2_t*)bufB;
    half2_t* a2p = (half2_t*)offb;
    __half*  attnh = (__half*)offb;                 // a2p dead after gate2
    half4_t* wA_off = (half4_t*)wt_offf;
    half4_t* wA_dc  = (half4_t*)wt_dcf;
    half4_t* wA_u1 = (half4_t*)wt_u1f;
    half4_t* wA_u2 = (half4_t*)wt_u2f;
    half2_t* wt_p1h  = (half2_t*)pt_p1;
    half2_t* wt_p2h  = (half2_t*)pt_p2;
    half2_t* wt_prh  = (half2_t*)pt_pr;

    dim3 blk(256);
    dim3 gpos(SVOL / 256, NB);
    dim3 g4(SVOL / 256, 4, NB);
    dim3 gmf(512, NB);                 // MFMA conv kernels: 8x8x8 spatial tiles
    dim3 g1w(SVOL / 64, 3, NB);        // deform: 1-wave blocks, 3072 total
    dim3 gdwc(8, CCH, NB);
    dim3 gtr(SVOL / 64, NB);

    hipLaunchKernelGGL(reshape_mfma_off_kernel, dim3((31104 + 255) / 256), blk, 0, stream, off_w, wA_off);
    hipLaunchKernelGGL(reshape_mfma48_kernel, dim3((15552 + 255) / 256), blk, 0, stream, u1_w, wA_u1);
    hipLaunchKernelGGL(reshape_mfma48_kernel, dim3((15552 + 255) / 256), blk, 0, stream, u2_w, wA_u2);
    hipLaunchKernelGGL(reshape_mfma_dc_kernel, dim3((15552 + 255) / 256), blk, 0, stream, dc_w, wA_dc);
    hipLaunchKernelGGL(t1x1_pair_kernel, dim3(5), blk, 0, stream, p1_w, wt_p1h);
    hipLaunchKernelGGL(t1x1_pair_kernel, dim3(5), blk, 0, stream, p2_w, wt_p2h);
    hipLaunchKernelGGL(t1x1_pair_kernel, dim3(5), blk, 0, stream, pr_w, wt_prh);
    hipLaunchKernelGGL(t1x1_kernel, dim3(9), blk, 0, stream, c1_w, pt_c1);
    hipLaunchKernelGGL(cb_kernel, dim3(1), dim3(64), 0, stream, c1_w, c1_b, dc_b, cb_all);

    hipLaunchKernelGGL(ln_kernel,            gpos, blk, 0, stream, x, ln_s, ln_b, xn, xnp);
    hipLaunchKernelGGL(p1_gelu_kernel,       g4,   blk, 0, stream, xnp, wt_p1h, p1_b, ubuf);
    hipLaunchKernelGGL(dw5_kernel,           gdwc, blk, 0, stream, ubuf, c0_w, c0_b, bufA);
    hipLaunchKernelGGL(dw7_kernel,           gdwc, blk, 0, stream, bufA, cs_w, cs_b, bufB);
    hipLaunchKernelGGL(transpose_pack_kernel, gtr, blk, 0, stream, bufB, a1h);
    hipLaunchKernelGGL(offconv_mfma_kernel,  gmf,  blk, 0, stream, a1h, wA_off, offb);
    hipMemsetAsync(bufB, 0, TS * sizeof(float), stream);
    hipLaunchKernelGGL(deform_mfma_kernel,   g1w,  dim3(64), 0, stream, a1h, offb, off_b, wA_dc, bufB);
    hipLaunchKernelGGL(gate1_kernel,         g4,   blk, 0, stream, bufB, ubuf, pt_c1, cb_all, a2p);
    hipLaunchKernelGGL(gate2_kernel,         g4,   blk, 0, stream, a2p, xn, x, wt_p2h, p2_b, gamma,
                       bufA, skh);
    hipLaunchKernelGGL(u1_mfma_kernel,       gmf,  blk, 0, stream, skh, wA_u1,
                       bn1_s, bn1_b, bn1_m, bn1_v, h1h);
    hipLaunchKernelGGL(u2_mfma_kernel,       gmf,  blk, 0, stream, h1h, bufA, wA_u2,
                       bn2_s, bn2_b, bn2_m, bn2_v, attnh);
    hipLaunchKernelGGL(pr_final_kernel,      g4,   blk, 0, stream, attnh, bufA, wt_prh, pr_b, out);
}